// Round 2
// baseline (4745.506 us; speedup 1.0000x reference)
//
#include <hip/hip_runtime.h>
#include <math.h>

// B=512, N=128, E=256, H=8, D=32. All fp32 (argmax fidelity requires it).
//
// Round-2 design:
//  precompute (k_gemm): kT = (emb@W1+b1)^T per b, v = emb@W2+b2, lkT = (emb@Wc+bc)^T,
//                       sq = emb@Wstep[E:2E]   (Wc = W3·Wmlp^T folds the MLP into logits)
//  rollout (k_roll): 256 blocks x 1024 threads, 2 batch elems per block.
//    Each 512-thread half holds its b's k, v, lk2 ENTIRELY IN REGISTERS
//    (64+64+64 VGPRs/thread). Per step the only global read is the 1KB
//    stepq[cur] row -> the 25 GB/steploop cache streaming of round 1 is gone.
//  Fallback to the round-1 kernels if ws_size is too small.

#define B_ 512
#define N_ 128
#define E_ 256
#define H_ 8
#define D_ 32
#define NEG (-1.0e9f)
#define CLIPV 10.0f
#define SCALE 0.17677669529663688110f  /* 1/sqrt(32), fp32-rounded */

// ---------------------------------------------------------------- K0: weight folds
__global__ void k0_prep(const float* __restrict__ Wqkv, const float* __restrict__ bqkv,
                        const float* __restrict__ Wmlp, const float* __restrict__ bmlp,
                        float* __restrict__ Wc, float* __restrict__ bc,
                        float* __restrict__ wc2, float* __restrict__ cconst) {
  int t = threadIdx.x;
  int blk = blockIdx.x;
  __shared__ float row_s[E_];
  if (blk < E_) {
    // Wc[g][f] = sum_e W3[g][e] * Wmlp[f][e]
    int g = blk;
    row_s[t] = Wqkv[g * 768 + 512 + t];
    __syncthreads();
    int f = t;
    const float4* wm4 = (const float4*)(Wmlp + f * E_);
    const float4* w34 = (const float4*)row_s;
    float acc = 0.f;
#pragma unroll 8
    for (int j = 0; j < E_ / 4; ++j) {
      float4 a = w34[j]; float4 bv = wm4[j];
      acc += a.x * bv.x + a.y * bv.y + a.z * bv.z + a.w * bv.w;
    }
    Wc[g * E_ + f] = acc;
  } else {
    // bc[f] = sum_e b3[e]*Wmlp[f][e];  wc2[g] = sum_e W3[g][e]*bmlp[e]
    int f = t;
    float a1 = 0.f, a2 = 0.f;
    for (int e = 0; e < E_; ++e) {
      a1 += bqkv[512 + e] * Wmlp[f * E_ + e];
      a2 += Wqkv[f * 768 + 512 + e] * bmlp[e];
    }
    bc[f] = a1;
    wc2[f] = a2;
    if (t == 0) {
      float c = 0.f;
      for (int e = 0; e < E_; ++e) c += bqkv[512 + e] * bmlp[e];
      *cconst = c;
    }
  }
}

// ---------------------------------------------------------------- K1: fused precompute GEMM
// out = emb(65536x256) @ {W1,W2,Wc,WstepBot}. A-tile (64 rows, full K) staged k-major in
// 64KB LDS; B streamed from L2. tmask bit (cc>>1): store that tensor transposed per b
// as out[b][e][n] (for coalesced register loads in k_roll).
__global__ __launch_bounds__(256, 2)
void k_gemm(const float* __restrict__ emb, const float* __restrict__ Wqkv,
            const float* __restrict__ bqkv, const float* __restrict__ Wstep,
            const float* __restrict__ Wc, const float* __restrict__ bc,
            float* __restrict__ kk_, float* __restrict__ vv_,
            float* __restrict__ lk2, float* __restrict__ sq, int ncc, int tmask) {
  __shared__ float As[256 * 64];  // [kk][m], exactly 64 KiB
  int t = threadIdx.x;
  int r0 = blockIdx.x * 64;
  {
    int m = t >> 2;           // 0..63
    int c0 = t & 3;
    const float4* e4 = (const float4*)emb;
#pragma unroll
    for (int p = 0; p < 16; ++p) {
      int c4 = c0 + p * 4;    // float4 column 0..63
      float4 a = e4[(size_t)(r0 + m) * 64 + c4];
      As[(c4 * 4 + 0) * 64 + m] = a.x;
      As[(c4 * 4 + 1) * 64 + m] = a.y;
      As[(c4 * 4 + 2) * 64 + m] = a.z;
      As[(c4 * 4 + 3) * 64 + m] = a.w;
    }
  }
  __syncthreads();
  int tx = t & 15, ty = t >> 4;
  const float4* As4 = (const float4*)As;
  for (int cc = 0; cc < ncc; ++cc) {
    const float* Bp; int ldb4; const float* bias; float* outp;
    int colbase = (cc & 1) * 128;
    switch (cc >> 1) {
      case 0:  Bp = Wqkv + colbase;          ldb4 = 192; bias = bqkv + colbase;       outp = kk_; break;
      case 1:  Bp = Wqkv + 256 + colbase;    ldb4 = 192; bias = bqkv + 256 + colbase; outp = vv_; break;
      case 2:  Bp = Wc + colbase;            ldb4 = 64;  bias = bc + colbase;         outp = lk2; break;
      default: Bp = Wstep + 65536 + colbase; ldb4 = 64;  bias = nullptr;              outp = sq;  break;
    }
    const float4* B4 = (const float4*)Bp;
    float acc[4][8];
#pragma unroll
    for (int i = 0; i < 4; ++i)
#pragma unroll
      for (int j = 0; j < 8; ++j) acc[i][j] = 0.f;

#pragma unroll 4
    for (int kk = 0; kk < 256; ++kk) {
      float4 b0 = B4[kk * ldb4 + tx * 2];
      float4 b1 = B4[kk * ldb4 + tx * 2 + 1];
      float4 av = As4[kk * 16 + ty];
      float a_[4] = {av.x, av.y, av.z, av.w};
#pragma unroll
      for (int i = 0; i < 4; ++i) {
        acc[i][0] += a_[i] * b0.x; acc[i][1] += a_[i] * b0.y;
        acc[i][2] += a_[i] * b0.z; acc[i][3] += a_[i] * b0.w;
        acc[i][4] += a_[i] * b1.x; acc[i][5] += a_[i] * b1.y;
        acc[i][6] += a_[i] * b1.z; acc[i][7] += a_[i] * b1.w;
      }
    }
    float bj[8];
#pragma unroll
    for (int j = 0; j < 8; ++j) bj[j] = bias ? bias[tx * 8 + j] : 0.f;
    int tr = (tmask >> (cc >> 1)) & 1;
    if (!tr) {
#pragma unroll
      for (int i = 0; i < 4; ++i) {
        int row = r0 + ty * 4 + i;
        float4 o0 = make_float4(acc[i][0] + bj[0], acc[i][1] + bj[1], acc[i][2] + bj[2], acc[i][3] + bj[3]);
        float4 o1 = make_float4(acc[i][4] + bj[4], acc[i][5] + bj[5], acc[i][6] + bj[6], acc[i][7] + bj[7]);
        float4* o4 = (float4*)(outp + (size_t)row * 256 + colbase + tx * 8);
        o4[0] = o0; o4[1] = o1;
      }
    } else {
      // out[b][e][n] = val ; b = row>>7, n = row&127, e = colbase + tx*8 + j
#pragma unroll
      for (int i = 0; i < 4; ++i) {
        int row = r0 + ty * 4 + i;
        int bb = row >> 7, nn = row & 127;
        float* op = outp + (size_t)bb * 32768 + nn;
#pragma unroll
        for (int j = 0; j < 8; ++j)
          op[(size_t)(colbase + tx * 8 + j) * 128] = acc[i][j] + bj[j];
      }
    }
  }
}

// ---------------------------------------------------------------- K2: qbase per b
__global__ void k_qbase(const float* __restrict__ emb, const float* __restrict__ Wfix,
                        const float* __restrict__ bfix, const float* __restrict__ Wstep,
                        const float* __restrict__ bstep, float* __restrict__ qbase) {
  int b = blockIdx.x, t = threadIdx.x;
  __shared__ float ge[E_], fi[E_];
  const float* eb = emb + (size_t)b * N_ * E_;
  float s = 0.f;
#pragma unroll 8
  for (int n = 0; n < N_; ++n) s += eb[n * E_ + t];
  ge[t] = s * (1.0f / 128.0f);
  fi[t] = eb[t];
  __syncthreads();
  float acc = bfix[t] + bstep[t];
#pragma unroll 4
  for (int g = 0; g < E_; ++g)
    acc += ge[g] * Wfix[g * E_ + t] + fi[g] * Wstep[g * E_ + t];
  qbase[b * E_ + t] = acc;
}

// ---------------------------------------------------------------- K3: c[b,n]
__global__ void k_c(const float* __restrict__ emb, const float* __restrict__ wc2,
                    const float* __restrict__ cconst, float* __restrict__ cvec) {
  __shared__ float w[E_];
  int t = threadIdx.x;
  w[t] = wc2[t];
  __syncthreads();
  int row = blockIdx.x * 256 + t;
  const float4* e4 = (const float4*)(emb + (size_t)row * E_);
  const float4* w4 = (const float4*)w;
  float acc = 0.f;
#pragma unroll 8
  for (int j = 0; j < E_ / 4; ++j) {
    float4 a = e4[j], bv = w4[j];
    acc += a.x * bv.x + a.y * bv.y + a.z * bv.z + a.w * bv.w;
  }
  cvec[row] = acc + *cconst;
}

// ---------------------------------------------------------------- K4: register-resident rollout
// 256 blocks x 1024 threads; 2 batch elems per block (sb = t>>9). Per 512-thread half:
//   k_reg[2][32]: (h = c*4 + lt>>7, n = lt&127), from kT[b][e][n]  (coalesced)
//   v_reg[64]   : (e = lt&255, n = (lt>>8)*64+j), from v[b][n][e]  (coalesced)
//   l_reg[64]   : (n = lt&127, e = (lt>>7)*64+j), from lkT[b][e][n](coalesced)
// Per step, only global read = stepq[cur] row (1KB) + nothing else.
__global__ __launch_bounds__(1024, 2)
void k_roll(const float* __restrict__ kT, const float* __restrict__ vv_,
            const float* __restrict__ lkT, const float* __restrict__ sq,
            const float* __restrict__ qbase, const float* __restrict__ cvec,
            float* __restrict__ out) {
  int t = threadIdx.x;
  int sb = t >> 9, lt = t & 511;
  int b = blockIdx.x * 2 + sb;

  __shared__ float q_s[2][256];
  __shared__ float sc_s[2][8][128];
  __shared__ float at_s[2][8][128];
  __shared__ float pctx[2][512];
  __shared__ float ctx_s[2][256];
  __shared__ float zq[2][512];
  __shared__ float zredv[2][2];
  __shared__ int   zredi[2][2];
  __shared__ float sred[2][2];
  __shared__ int   vis[2][128];
  __shared__ int   cur_s[2];

  const float* kTb = kT + (size_t)b * 32768;
  const float* vb  = vv_ + (size_t)b * 32768;
  const float* lTb = lkT + (size_t)b * 32768;
  const float* sqb = sq + (size_t)b * 32768;

  int kn = lt & 127, kh0 = lt >> 7;   // score phase: head pair base, node
  int ve = lt & 255, vnh = lt >> 8;   // ctx phase
  int ln = lt & 127, leq = lt >> 7;   // z phase

  float k_reg[2][32];
#pragma unroll
  for (int c = 0; c < 2; ++c) {
    int h = c * 4 + kh0;
#pragma unroll
    for (int d = 0; d < 32; ++d)
      k_reg[c][d] = kTb[(h * 32 + d) * 128 + kn];
  }
  float v_reg[64];
#pragma unroll
  for (int j = 0; j < 64; ++j) v_reg[j] = vb[(vnh * 64 + j) * 256 + ve];
  float l_reg[64];
#pragma unroll
  for (int j = 0; j < 64; ++j) l_reg[j] = lTb[(leq * 64 + j) * 128 + ln];

  float qb_r = (lt < 256) ? qbase[b * 256 + lt] : 0.f;
  float cb_r = (lt < 128) ? cvec[b * 128 + lt] : 0.f;

  if (lt < 128) vis[sb][lt] = (lt == 0) ? 1 : 0;
  if (lt == 0) cur_s[sb] = 0;
  float lp = 0.f;
  __syncthreads();

#pragma unroll 1
  for (int it = 0; it < N_ - 1; ++it) {
    int cur = cur_s[sb];
    // --- q = qbase + stepq[cur]
    if (lt < 256) q_s[sb][lt] = qb_r + sqb[cur * 256 + lt];
    __syncthreads();

    // --- scores: thread owns (h = c*4+kh0, n = kn); q via broadcast float4 LDS reads
#pragma unroll
    for (int c = 0; c < 2; ++c) {
      int h = c * 4 + kh0;
      const float4* q4 = (const float4*)(q_s[sb] + h * 32);
      float acc = 0.f;
#pragma unroll
      for (int dd = 0; dd < 8; ++dd) {
        float4 qv = q4[dd];
        acc += qv.x * k_reg[c][dd * 4]     + qv.y * k_reg[c][dd * 4 + 1]
             + qv.z * k_reg[c][dd * 4 + 2] + qv.w * k_reg[c][dd * 4 + 3];
      }
      sc_s[sb][h][kn] = vis[sb][kn] ? NEG : acc * SCALE;
    }
    __syncthreads();

    // --- masked softmax: one wave per head
    {
      int h = lt >> 6, lane = lt & 63;
      float s0 = sc_s[sb][h][lane], s1 = sc_s[sb][h][lane + 64];
      float m = fmaxf(s0, s1);
#pragma unroll
      for (int o = 32; o > 0; o >>= 1) m = fmaxf(m, __shfl_xor(m, o));
      float e0 = expf(s0 - m), e1 = expf(s1 - m);
      float ss = e0 + e1;
#pragma unroll
      for (int o = 32; o > 0; o >>= 1) ss += __shfl_xor(ss, o);
      at_s[sb][h][lane] = e0 / ss;
      at_s[sb][h][lane + 64] = e1 / ss;
    }
    __syncthreads();

    // --- ctx partial: thread owns e=ve, n-half vnh
    {
      const float4* a4 = (const float4*)(at_s[sb][ve >> 5] + vnh * 64);
      float acc = 0.f;
#pragma unroll
      for (int jj = 0; jj < 16; ++jj) {
        float4 av = a4[jj];
        acc += av.x * v_reg[jj * 4]     + av.y * v_reg[jj * 4 + 1]
             + av.z * v_reg[jj * 4 + 2] + av.w * v_reg[jj * 4 + 3];
      }
      pctx[sb][lt] = acc;
    }
    __syncthreads();
    if (lt < 256) ctx_s[sb][lt] = pctx[sb][lt] + pctx[sb][lt + 256];
    __syncthreads();

    // --- z partial: thread owns n=ln, e-quarter leq
    {
      const float4* c4 = (const float4*)(ctx_s[sb] + leq * 64);
      float acc = 0.f;
#pragma unroll
      for (int jj = 0; jj < 16; ++jj) {
        float4 cv = c4[jj];
        acc += cv.x * l_reg[jj * 4]     + cv.y * l_reg[jj * 4 + 1]
             + cv.z * l_reg[jj * 4 + 2] + cv.w * l_reg[jj * 4 + 3];
      }
      zq[sb][lt] = acc;
    }
    __syncthreads();

    // --- z assemble + argmax (first-index tiebreak)
    float zv = 0.f;
    int wv = (lt >> 6) & 1;
    if (lt < 128) {
      zv = zq[sb][lt] + zq[sb][lt + 128] + zq[sb][lt + 256] + zq[sb][lt + 384] + cb_r;
      float val = vis[sb][lt] ? -1e30f : zv;
      int idx = lt;
#pragma unroll
      for (int o = 32; o > 0; o >>= 1) {
        float ov = __shfl_xor(val, o);
        int oi = __shfl_xor(idx, o);
        if (ov > val || (ov == val && oi < idx)) { val = ov; idx = oi; }
      }
      if ((lt & 63) == 0) { zredv[sb][wv] = val; zredi[sb][wv] = idx; }
    }
    __syncthreads();
    float v0 = zredv[sb][0], v1 = zredv[sb][1];
    int i0 = zredi[sb][0], i1 = zredi[sb][1];
    int action; float vmax;
    if (v1 > v0 || (v1 == v0 && i1 < i0)) { action = i1; vmax = v1; }
    else                                  { action = i0; vmax = v0; }

    // --- lse over unvisited (chosen logp = -log S)
    if (lt < 128) {
      float lmax = CLIPV * tanhf(vmax * SCALE);
      float term = 0.f;
      if (!vis[sb][lt]) term = expf(CLIPV * tanhf(zv * SCALE) - lmax);
#pragma unroll
      for (int o = 32; o > 0; o >>= 1) term += __shfl_xor(term, o);
      if ((lt & 63) == 0) sred[sb][wv] = term;
    }
    __syncthreads();
    if (lt == 0) {
      float S = sred[sb][0] + sred[sb][1];
      lp -= logf(S);
      cur_s[sb] = action;
      vis[sb][action] = 1;
    }
    __syncthreads();
  }
  if (lt == 0) out[b] = lp;
}

// ---------------------------------------------------------------- K4-fallback (round-1 proven)
__global__ __launch_bounds__(256, 2)
void k_loop(const float* __restrict__ emb, const float* __restrict__ Wstep,
            const float* __restrict__ kk_, const float* __restrict__ vv_,
            const float* __restrict__ lk2, const float* __restrict__ sq,
            const float* __restrict__ qbase, const float* __restrict__ cvec,
            float* __restrict__ out, int has_sq) {
  int b = blockIdx.x, t = threadIdx.x;
  __shared__ float q_s[E_];
  __shared__ float attn_s[H_ * N_];
  __shared__ float ctx_s[E_];
  __shared__ float zpart[2 * N_];
  __shared__ float embc[E_];
  __shared__ float redv[2];
  __shared__ int   redi[2];
  __shared__ float reds[4];
  __shared__ int   vis[N_];
  __shared__ int   cur_s;

  if (t < N_) vis[t] = (t == 0) ? 1 : 0;
  if (t == 0) cur_s = 0;
  float lp = 0.f;
  __syncthreads();

  const float* kb = kk_ + (size_t)b * N_ * E_;
  const float* vb = vv_ + (size_t)b * N_ * E_ + t;
  const float* lb = lk2 + (size_t)b * N_ * E_;
  const float* qb = qbase + b * E_;
  const float* cb = cvec + b * N_;
  const float* eb = emb + (size_t)b * N_ * E_;

  int h = t >> 5;
  int n0 = (t & 31) * 4;

#pragma unroll 1
  for (int it = 0; it < N_ - 1; ++it) {
    int cur = cur_s;
    if (has_sq) {
      q_s[t] = qb[t] + sq[((size_t)b * N_ + cur) * E_ + t];
    } else {
      embc[t] = eb[cur * E_ + t];
      __syncthreads();
      float a = qb[t];
#pragma unroll 4
      for (int g = 0; g < E_; ++g) a += embc[g] * Wstep[(E_ + g) * E_ + t];
      q_s[t] = a;
    }
    __syncthreads();

    float qv[32];
    {
      const float4* q4 = (const float4*)(q_s + h * 32);
#pragma unroll
      for (int j = 0; j < 8; ++j) {
        float4 x = q4[j];
        qv[j * 4] = x.x; qv[j * 4 + 1] = x.y; qv[j * 4 + 2] = x.z; qv[j * 4 + 3] = x.w;
      }
    }
    float si[4];
#pragma unroll
    for (int i = 0; i < 4; ++i) {
      int n = n0 + i;
      const float4* k4 = (const float4*)(kb + n * E_ + h * 32);
      float acc = 0.f;
#pragma unroll
      for (int j = 0; j < 8; ++j) {
        float4 x = k4[j];
        acc += qv[j * 4] * x.x + qv[j * 4 + 1] * x.y + qv[j * 4 + 2] * x.z + qv[j * 4 + 3] * x.w;
      }
      acc *= SCALE;
      si[i] = vis[n] ? NEG : acc;
    }
    float m = fmaxf(fmaxf(si[0], si[1]), fmaxf(si[2], si[3]));
#pragma unroll
    for (int o = 16; o > 0; o >>= 1) m = fmaxf(m, __shfl_xor(m, o, 32));
    float ei[4]; float ps = 0.f;
#pragma unroll
    for (int i = 0; i < 4; ++i) { ei[i] = expf(si[i] - m); ps += ei[i]; }
#pragma unroll
    for (int o = 16; o > 0; o >>= 1) ps += __shfl_xor(ps, o, 32);
#pragma unroll
    for (int i = 0; i < 4; ++i) attn_s[h * N_ + n0 + i] = ei[i] / ps;
    __syncthreads();

    {
      int h2 = t >> 5;
      const float* ar = attn_s + h2 * N_;
      float acc = 0.f;
#pragma unroll 8
      for (int n = 0; n < N_; ++n) acc += ar[n] * vb[n * E_];
      ctx_s[t] = acc;
    }
    __syncthreads();

    {
      int n = t & 127, half = t >> 7;
      const float4* l4 = (const float4*)(lb + n * E_ + half * 128);
      const float4* c4 = (const float4*)(ctx_s + half * 128);
      float acc = 0.f;
#pragma unroll 4
      for (int j = 0; j < 32; ++j) {
        float4 x = l4[j], y = c4[j];
        acc += x.x * y.x + x.y * y.y + x.z * y.z + x.w * y.w;
      }
      zpart[t] = acc;
    }
    __syncthreads();

    float zv = 0.f, zmv = -1e30f;
    if (t < N_) {
      zv = zpart[t] + zpart[t + N_] + cb[t];
      zmv = vis[t] ? -1e30f : zv;
    }
    float val = zmv; int idx = t & 127;
#pragma unroll
    for (int o = 32; o > 0; o >>= 1) {
      float ov = __shfl_xor(val, o);
      int oi = __shfl_xor(idx, o);
      if (ov > val || (ov == val && oi < idx)) { val = ov; idx = oi; }
    }
    if (t == 0 || t == 64) { redv[t >> 6] = val; redi[t >> 6] = idx; }
    __syncthreads();
    float v0 = redv[0], v1 = redv[1]; int i0 = redi[0], i1 = redi[1];
    int action; float vmax;
    if (v1 > v0 || (v1 == v0 && i1 < i0)) { action = i1; vmax = v1; }
    else                                  { action = i0; vmax = v0; }
    float lmax = CLIPV * tanhf(vmax * SCALE);
    float term = 0.f;
    if (t < N_ && !vis[t]) {
      float lg = CLIPV * tanhf(zv * SCALE);
      term = expf(lg - lmax);
    }
    float s = term;
#pragma unroll
    for (int o = 32; o > 0; o >>= 1) s += __shfl_xor(s, o);
    __syncthreads();
    if ((t & 63) == 0) reds[t >> 6] = s;
    __syncthreads();
    if (t == 0) {
      float S = reds[0] + reds[1] + reds[2] + reds[3];
      lp -= logf(S);
      cur_s = action;
      vis[action] = 1;
    }
    __syncthreads();
  }
  if (t == 0) out[b] = lp;
}

// ---------------------------------------------------------------- launch
extern "C" void kernel_launch(void* const* d_in, const int* in_sizes, int n_in,
                              void* d_out, int out_size, void* d_ws, size_t ws_size,
                              hipStream_t stream) {
  (void)in_sizes; (void)n_in; (void)out_size;
  const float* emb   = (const float*)d_in[0];
  const float* Wqkv  = (const float*)d_in[1];
  const float* bqkv  = (const float*)d_in[2];
  const float* Wfix  = (const float*)d_in[3];
  const float* bfix  = (const float*)d_in[4];
  const float* Wstep = (const float*)d_in[5];
  const float* bstep = (const float*)d_in[6];
  const float* Wmlp  = (const float*)d_in[7];
  const float* bmlp  = (const float*)d_in[8];
  float* out = (float*)d_out;
  float* ws = (float*)d_ws;

  const size_t NBE = (size_t)B_ * N_ * E_;  // 16,777,216 floats
  float* kk_    = ws;                  // kT in fast path
  float* vv_    = ws + NBE;
  float* lk2    = ws + 2 * NBE;        // lkT in fast path
  float* qbase  = ws + 3 * NBE;        // 131072
  float* cvec   = qbase + 131072;      // 65536
  float* Wc     = cvec + 65536;        // 65536
  float* bc     = Wc + 65536;          // 256
  float* wc2    = bc + 256;            // 256
  float* cconst = wc2 + 256;           // (64 pad)
  float* sq     = cconst + 64;         // NBE floats
  size_t need_sq = (size_t)((sq - ws) + NBE) * sizeof(float);
  int has_sq = (ws_size >= need_sq) ? 1 : 0;

  hipLaunchKernelGGL(k0_prep, dim3(257), dim3(256), 0, stream,
                     Wqkv, bqkv, Wmlp, bmlp, Wc, bc, wc2, cconst);
  hipLaunchKernelGGL(k_qbase, dim3(512), dim3(256), 0, stream,
                     emb, Wfix, bfix, Wstep, bstep, qbase);
  hipLaunchKernelGGL(k_c, dim3(256), dim3(256), 0, stream,
                     emb, wc2, cconst, cvec);
  if (has_sq) {
    // fast path: k and lk2 stored transposed per b, register-resident rollout
    hipLaunchKernelGGL(k_gemm, dim3(1024), dim3(256), 0, stream,
                       emb, Wqkv, bqkv, Wstep, Wc, bc, kk_, vv_, lk2, sq, 8, 0b0101);
    hipLaunchKernelGGL(k_roll, dim3(256), dim3(1024), 0, stream,
                       kk_, vv_, lk2, sq, qbase, cvec, out);
  } else {
    hipLaunchKernelGGL(k_gemm, dim3(1024), dim3(256), 0, stream,
                       emb, Wqkv, bqkv, Wstep, Wc, bc, kk_, vv_, lk2, sq, 6, 0);
    hipLaunchKernelGGL(k_loop, dim3(512), dim3(256), 0, stream,
                       emb, Wstep, kk_, vv_, lk2, sq, qbase, cvec, out, 0);
  }
}

// Round 3
// 1656.471 us; speedup vs baseline: 2.8648x; 2.8648x over previous
//
#include <hip/hip_runtime.h>
#include <math.h>

// B=512, N=128, E=256, H=8, D=32. All fp32 (argmax fidelity requires it).
//
// Round-3 design (fits the known-good 202.4MB ws footprint):
//  k_gemm: kT = (emb@W1+b1)^T per b, v = emb@W2+b2, lkT = (emb@Wc+bc)^T  (3 tensors only)
//  k_roll: 512 blocks x 512 threads, one b per block, 1 block/CU.
//    k/v/lk2 in REGISTERS (64+64+64 VGPRs/thread). sq = emb[b]@WstepBot computed
//    per block at init into 130KB LDS. Per-step memory traffic = LDS only.

#define B_ 512
#define N_ 128
#define E_ 256
#define H_ 8
#define D_ 32
#define NEG (-1.0e9f)
#define CLIPV 10.0f
#define SCALE 0.17677669529663688110f  /* 1/sqrt(32), fp32-rounded */

// ---------------------------------------------------------------- K0: weight folds
__global__ void k0_prep(const float* __restrict__ Wqkv, const float* __restrict__ bqkv,
                        const float* __restrict__ Wmlp, const float* __restrict__ bmlp,
                        float* __restrict__ Wc, float* __restrict__ bc,
                        float* __restrict__ wc2, float* __restrict__ cconst) {
  int t = threadIdx.x;
  int blk = blockIdx.x;
  __shared__ float row_s[E_];
  if (blk < E_) {
    // Wc[g][f] = sum_e W3[g][e] * Wmlp[f][e]
    int g = blk;
    row_s[t] = Wqkv[g * 768 + 512 + t];
    __syncthreads();
    int f = t;
    const float4* wm4 = (const float4*)(Wmlp + f * E_);
    const float4* w34 = (const float4*)row_s;
    float acc = 0.f;
#pragma unroll 8
    for (int j = 0; j < E_ / 4; ++j) {
      float4 a = w34[j]; float4 bv = wm4[j];
      acc += a.x * bv.x + a.y * bv.y + a.z * bv.z + a.w * bv.w;
    }
    Wc[g * E_ + f] = acc;
  } else {
    // bc[f] = sum_e b3[e]*Wmlp[f][e];  wc2[g] = sum_e W3[g][e]*bmlp[e]
    int f = t;
    float a1 = 0.f, a2 = 0.f;
    for (int e = 0; e < E_; ++e) {
      a1 += bqkv[512 + e] * Wmlp[f * E_ + e];
      a2 += Wqkv[f * 768 + 512 + e] * bmlp[e];
    }
    bc[f] = a1;
    wc2[f] = a2;
    if (t == 0) {
      float c = 0.f;
      for (int e = 0; e < E_; ++e) c += bqkv[512 + e] * bmlp[e];
      *cconst = c;
    }
  }
}

// ---------------------------------------------------------------- K1: precompute GEMM (3 tensors)
// A-tile (64 rows, full K) staged k-major in 64KB LDS; B streamed from L2.
// tmask bit (cc>>1): store that tensor transposed per b as out[b][e][n].
__global__ __launch_bounds__(256, 2)
void k_gemm(const float* __restrict__ emb, const float* __restrict__ Wqkv,
            const float* __restrict__ bqkv,
            const float* __restrict__ Wc, const float* __restrict__ bc,
            float* __restrict__ kk_, float* __restrict__ vv_,
            float* __restrict__ lk2, int ncc, int tmask) {
  __shared__ float As[256 * 64];  // [kk][m], exactly 64 KiB
  int t = threadIdx.x;
  int r0 = blockIdx.x * 64;
  {
    int m = t >> 2;           // 0..63
    int c0 = t & 3;
    const float4* e4 = (const float4*)emb;
#pragma unroll
    for (int p = 0; p < 16; ++p) {
      int c4 = c0 + p * 4;    // float4 column 0..63
      float4 a = e4[(size_t)(r0 + m) * 64 + c4];
      As[(c4 * 4 + 0) * 64 + m] = a.x;
      As[(c4 * 4 + 1) * 64 + m] = a.y;
      As[(c4 * 4 + 2) * 64 + m] = a.z;
      As[(c4 * 4 + 3) * 64 + m] = a.w;
    }
  }
  __syncthreads();
  int tx = t & 15, ty = t >> 4;
  const float4* As4 = (const float4*)As;
  for (int cc = 0; cc < ncc; ++cc) {
    const float* Bp; int ldb4; const float* bias; float* outp;
    int colbase = (cc & 1) * 128;
    switch (cc >> 1) {
      case 0:  Bp = Wqkv + colbase;          ldb4 = 192; bias = bqkv + colbase;       outp = kk_; break;
      case 1:  Bp = Wqkv + 256 + colbase;    ldb4 = 192; bias = bqkv + 256 + colbase; outp = vv_; break;
      default: Bp = Wc + colbase;            ldb4 = 64;  bias = bc + colbase;         outp = lk2; break;
    }
    const float4* B4 = (const float4*)Bp;
    float acc[4][8];
#pragma unroll
    for (int i = 0; i < 4; ++i)
#pragma unroll
      for (int j = 0; j < 8; ++j) acc[i][j] = 0.f;

#pragma unroll 4
    for (int kk = 0; kk < 256; ++kk) {
      float4 b0 = B4[kk * ldb4 + tx * 2];
      float4 b1 = B4[kk * ldb4 + tx * 2 + 1];
      float4 av = As4[kk * 16 + ty];
      float a_[4] = {av.x, av.y, av.z, av.w};
#pragma unroll
      for (int i = 0; i < 4; ++i) {
        acc[i][0] += a_[i] * b0.x; acc[i][1] += a_[i] * b0.y;
        acc[i][2] += a_[i] * b0.z; acc[i][3] += a_[i] * b0.w;
        acc[i][4] += a_[i] * b1.x; acc[i][5] += a_[i] * b1.y;
        acc[i][6] += a_[i] * b1.z; acc[i][7] += a_[i] * b1.w;
      }
    }
    float bj[8];
#pragma unroll
    for (int j = 0; j < 8; ++j) bj[j] = bias ? bias[tx * 8 + j] : 0.f;
    int tr = (tmask >> (cc >> 1)) & 1;
    if (!tr) {
#pragma unroll
      for (int i = 0; i < 4; ++i) {
        int row = r0 + ty * 4 + i;
        float4 o0 = make_float4(acc[i][0] + bj[0], acc[i][1] + bj[1], acc[i][2] + bj[2], acc[i][3] + bj[3]);
        float4 o1 = make_float4(acc[i][4] + bj[4], acc[i][5] + bj[5], acc[i][6] + bj[6], acc[i][7] + bj[7]);
        float4* o4 = (float4*)(outp + (size_t)row * 256 + colbase + tx * 8);
        o4[0] = o0; o4[1] = o1;
      }
    } else {
      // out[b][e][n] ; b = row>>7, n = row&127, e = colbase + tx*8 + j
#pragma unroll
      for (int i = 0; i < 4; ++i) {
        int row = r0 + ty * 4 + i;
        int bb = row >> 7, nn = row & 127;
        float* op = outp + (size_t)bb * 32768 + nn;
#pragma unroll
        for (int j = 0; j < 8; ++j)
          op[(size_t)(colbase + tx * 8 + j) * 128] = acc[i][j] + bj[j];
      }
    }
  }
}

// ---------------------------------------------------------------- K2: qbase per b
__global__ void k_qbase(const float* __restrict__ emb, const float* __restrict__ Wfix,
                        const float* __restrict__ bfix, const float* __restrict__ Wstep,
                        const float* __restrict__ bstep, float* __restrict__ qbase) {
  int b = blockIdx.x, t = threadIdx.x;
  __shared__ float ge[E_], fi[E_];
  const float* eb = emb + (size_t)b * N_ * E_;
  float s = 0.f;
#pragma unroll 8
  for (int n = 0; n < N_; ++n) s += eb[n * E_ + t];
  ge[t] = s * (1.0f / 128.0f);
  fi[t] = eb[t];
  __syncthreads();
  float acc = bfix[t] + bstep[t];
#pragma unroll 4
  for (int g = 0; g < E_; ++g)
    acc += ge[g] * Wfix[g * E_ + t] + fi[g] * Wstep[g * E_ + t];
  qbase[b * E_ + t] = acc;
}

// ---------------------------------------------------------------- K3: c[b,n]
__global__ void k_c(const float* __restrict__ emb, const float* __restrict__ wc2,
                    const float* __restrict__ cconst, float* __restrict__ cvec) {
  __shared__ float w[E_];
  int t = threadIdx.x;
  w[t] = wc2[t];
  __syncthreads();
  int row = blockIdx.x * 256 + t;
  const float4* e4 = (const float4*)(emb + (size_t)row * E_);
  const float4* w4 = (const float4*)w;
  float acc = 0.f;
#pragma unroll 8
  for (int j = 0; j < E_ / 4; ++j) {
    float4 a = e4[j], bv = w4[j];
    acc += a.x * bv.x + a.y * bv.y + a.z * bv.z + a.w * bv.w;
  }
  cvec[row] = acc + *cconst;
}

// ---------------------------------------------------------------- K4: register-resident rollout
// One block (512 thr, 8 waves) per batch element. k/v/lk2 in registers; sq computed
// at init into LDS (row stride 260 to keep float4 alignment + avoid bank conflicts).
__global__ __launch_bounds__(512, 2)
void k_roll(const float* __restrict__ emb, const float* __restrict__ Wstep,
            const float* __restrict__ kT, const float* __restrict__ vv_,
            const float* __restrict__ lkT,
            const float* __restrict__ qbase, const float* __restrict__ cvec,
            float* __restrict__ out) {
  int lt = threadIdx.x;
  int b = blockIdx.x;

  __shared__ float sq_lds[128 * 260];   // 130 KiB
  __shared__ float work[6144];          // 24 KiB: init At[2048]+Bs[4096] / roll buffers
  __shared__ int   vis[128];
  __shared__ int   cur_s;
  __shared__ float zredv[2];
  __shared__ int   zredi[2];
  __shared__ float sred[2];

  if (lt < 128) vis[lt] = (lt == 0) ? 1 : 0;
  if (lt == 0) cur_s = 0;

  // ---- init phase A: sq[n][e] = sum_g emb[b][n][g] * Wstep[(256+g)*256+e] ----
  {
    float* At = work;           // [16][128]  A^T chunk
    float* Bs = work + 2048;    // [16][256]  B chunk
    const float4* eb4 = (const float4*)(emb + (size_t)b * 32768);
    const float* W2 = Wstep + 65536;
    int n0 = (lt & 31) * 4;
    int e0 = (lt >> 5) * 16;
    float acc[4][16];
#pragma unroll
    for (int i = 0; i < 4; ++i)
#pragma unroll
      for (int j = 0; j < 16; ++j) acc[i][j] = 0.f;

    for (int gc = 0; gc < 16; ++gc) {
      {
        int n = lt & 127, q4g = lt >> 7;
        float4 a = eb4[n * 64 + gc * 4 + q4g];
        At[(q4g * 4 + 0) * 128 + n] = a.x;
        At[(q4g * 4 + 1) * 128 + n] = a.y;
        At[(q4g * 4 + 2) * 128 + n] = a.z;
        At[(q4g * 4 + 3) * 128 + n] = a.w;
      }
      {
        const float4* w4 = (const float4*)(W2 + gc * 16 * 256);
        ((float4*)Bs)[lt] = w4[lt];
        ((float4*)Bs)[lt + 512] = w4[lt + 512];
      }
      __syncthreads();
#pragma unroll
      for (int gi = 0; gi < 16; ++gi) {
        float4 a4 = *(const float4*)(At + gi * 128 + n0);
        const float4* bp = (const float4*)(Bs + gi * 256 + e0);
        float4 b0 = bp[0], b1 = bp[1], b2 = bp[2], b3 = bp[3];
        float av[4] = {a4.x, a4.y, a4.z, a4.w};
        float bv[16] = {b0.x, b0.y, b0.z, b0.w, b1.x, b1.y, b1.z, b1.w,
                        b2.x, b2.y, b2.z, b2.w, b3.x, b3.y, b3.z, b3.w};
#pragma unroll
        for (int i = 0; i < 4; ++i)
#pragma unroll
          for (int j = 0; j < 16; ++j) acc[i][j] += av[i] * bv[j];
      }
      __syncthreads();
    }
#pragma unroll
    for (int i = 0; i < 4; ++i)
#pragma unroll
      for (int j4 = 0; j4 < 4; ++j4)
        *(float4*)(sq_lds + (n0 + i) * 260 + e0 + j4 * 4) =
            make_float4(acc[i][j4 * 4], acc[i][j4 * 4 + 1], acc[i][j4 * 4 + 2], acc[i][j4 * 4 + 3]);
  }

  // ---- init phase B: register fills (coalesced) ----
  const float* kTb = kT + (size_t)b * 32768;
  const float* vb  = vv_ + (size_t)b * 32768;
  const float* lTb = lkT + (size_t)b * 32768;

  int kn = lt & 127, kh0 = lt >> 7;   // score phase: node, head-quarter
  int ve = lt & 255, vnh = lt >> 8;   // ctx phase
  int ln = lt & 127, leq = lt >> 7;   // z phase

  float k_reg[2][32];
#pragma unroll
  for (int c = 0; c < 2; ++c) {
    int h = c * 4 + kh0;
#pragma unroll
    for (int d = 0; d < 32; ++d)
      k_reg[c][d] = kTb[(h * 32 + d) * 128 + kn];
  }
  float v_reg[64];
#pragma unroll
  for (int j = 0; j < 64; ++j) v_reg[j] = vb[(vnh * 64 + j) * 256 + ve];
  float l_reg[64];
#pragma unroll
  for (int j = 0; j < 64; ++j) l_reg[j] = lTb[(leq * 64 + j) * 128 + ln];

  float qb_r = (lt < 256) ? qbase[b * 256 + lt] : 0.f;
  float cb_r = (lt < 128) ? cvec[b * 128 + lt] : 0.f;
  float lp = 0.f;
  __syncthreads();

  // ---- rollout buffers in `work` ----
  float* q_s   = work;          // 256
  float* sc_s  = work + 256;    // 8*128
  float* at_s  = work + 1280;   // 8*128
  float* pctx  = work + 2304;   // 512
  float* ctx_s = work + 2816;   // 256
  float* zq    = work + 3072;   // 512

#pragma unroll 1
  for (int it = 0; it < N_ - 1; ++it) {
    int cur = cur_s;
    // --- q = qbase + sq[cur]
    if (lt < 256) q_s[lt] = qb_r + sq_lds[cur * 260 + lt];
    __syncthreads();

    // --- scores: thread owns (h = c*4+kh0, n = kn)
#pragma unroll
    for (int c = 0; c < 2; ++c) {
      int h = c * 4 + kh0;
      const float4* q4 = (const float4*)(q_s + h * 32);
      float acc = 0.f;
#pragma unroll
      for (int dd = 0; dd < 8; ++dd) {
        float4 qv = q4[dd];
        acc += qv.x * k_reg[c][dd * 4]     + qv.y * k_reg[c][dd * 4 + 1]
             + qv.z * k_reg[c][dd * 4 + 2] + qv.w * k_reg[c][dd * 4 + 3];
      }
      sc_s[h * 128 + kn] = vis[kn] ? NEG : acc * SCALE;
    }
    __syncthreads();

    // --- masked softmax: one wave per head
    {
      int h = lt >> 6, lane = lt & 63;
      float s0 = sc_s[h * 128 + lane], s1 = sc_s[h * 128 + lane + 64];
      float m = fmaxf(s0, s1);
#pragma unroll
      for (int o = 32; o > 0; o >>= 1) m = fmaxf(m, __shfl_xor(m, o));
      float e0 = expf(s0 - m), e1 = expf(s1 - m);
      float ss = e0 + e1;
#pragma unroll
      for (int o = 32; o > 0; o >>= 1) ss += __shfl_xor(ss, o);
      at_s[h * 128 + lane] = e0 / ss;
      at_s[h * 128 + lane + 64] = e1 / ss;
    }
    __syncthreads();

    // --- ctx partial: thread owns e=ve, n-half vnh
    {
      const float4* a4 = (const float4*)(at_s + (ve >> 5) * 128 + vnh * 64);
      float acc = 0.f;
#pragma unroll
      for (int jj = 0; jj < 16; ++jj) {
        float4 av = a4[jj];
        acc += av.x * v_reg[jj * 4]     + av.y * v_reg[jj * 4 + 1]
             + av.z * v_reg[jj * 4 + 2] + av.w * v_reg[jj * 4 + 3];
      }
      pctx[lt] = acc;
    }
    __syncthreads();
    if (lt < 256) ctx_s[lt] = pctx[lt] + pctx[lt + 256];
    __syncthreads();

    // --- z partial: thread owns n=ln, e-quarter leq
    {
      const float4* c4 = (const float4*)(ctx_s + leq * 64);
      float acc = 0.f;
#pragma unroll
      for (int jj = 0; jj < 16; ++jj) {
        float4 cv = c4[jj];
        acc += cv.x * l_reg[jj * 4]     + cv.y * l_reg[jj * 4 + 1]
             + cv.z * l_reg[jj * 4 + 2] + cv.w * l_reg[jj * 4 + 3];
      }
      zq[lt] = acc;
    }
    __syncthreads();

    // --- z assemble + argmax (first-index tiebreak)
    float zv = 0.f;
    int wv = (lt >> 6) & 1;
    if (lt < 128) {
      zv = zq[lt] + zq[lt + 128] + zq[lt + 256] + zq[lt + 384] + cb_r;
      float val = vis[lt] ? -1e30f : zv;
      int idx = lt;
#pragma unroll
      for (int o = 32; o > 0; o >>= 1) {
        float ov = __shfl_xor(val, o);
        int oi = __shfl_xor(idx, o);
        if (ov > val || (ov == val && oi < idx)) { val = ov; idx = oi; }
      }
      if ((lt & 63) == 0) { zredv[wv] = val; zredi[wv] = idx; }
    }
    __syncthreads();
    float v0 = zredv[0], v1 = zredv[1];
    int i0 = zredi[0], i1 = zredi[1];
    int action; float vmax;
    if (v1 > v0 || (v1 == v0 && i1 < i0)) { action = i1; vmax = v1; }
    else                                  { action = i0; vmax = v0; }

    // --- lse over unvisited (chosen logp = -log S)
    if (lt < 128) {
      float lmax = CLIPV * tanhf(vmax * SCALE);
      float term = 0.f;
      if (!vis[lt]) term = expf(CLIPV * tanhf(zv * SCALE) - lmax);
#pragma unroll
      for (int o = 32; o > 0; o >>= 1) term += __shfl_xor(term, o);
      if ((lt & 63) == 0) sred[wv] = term;
    }
    __syncthreads();
    if (lt == 0) {
      float S = sred[0] + sred[1];
      lp -= logf(S);
      cur_s = action;
      vis[action] = 1;
    }
    __syncthreads();
  }
  if (lt == 0) out[b] = lp;
}

// ---------------------------------------------------------------- launch
extern "C" void kernel_launch(void* const* d_in, const int* in_sizes, int n_in,
                              void* d_out, int out_size, void* d_ws, size_t ws_size,
                              hipStream_t stream) {
  (void)in_sizes; (void)n_in; (void)out_size; (void)ws_size;
  const float* emb   = (const float*)d_in[0];
  const float* Wqkv  = (const float*)d_in[1];
  const float* bqkv  = (const float*)d_in[2];
  const float* Wfix  = (const float*)d_in[3];
  const float* bfix  = (const float*)d_in[4];
  const float* Wstep = (const float*)d_in[5];
  const float* bstep = (const float*)d_in[6];
  const float* Wmlp  = (const float*)d_in[7];
  const float* bmlp  = (const float*)d_in[8];
  float* out = (float*)d_out;
  float* ws = (float*)d_ws;

  const size_t NBE = (size_t)B_ * N_ * E_;  // 16,777,216 floats
  float* kk_    = ws;                  // kT
  float* vv_    = ws + NBE;            // v
  float* lk2    = ws + 2 * NBE;        // lkT
  float* qbase  = ws + 3 * NBE;        // 131072
  float* cvec   = qbase + 131072;      // 65536
  float* Wc     = cvec + 65536;        // 65536
  float* bc     = Wc + 65536;          // 256
  float* wc2    = bc + 256;            // 256
  float* cconst = wc2 + 256;           // (64 pad)   total = round-1 footprint (known good)

  hipLaunchKernelGGL(k0_prep, dim3(257), dim3(256), 0, stream,
                     Wqkv, bqkv, Wmlp, bmlp, Wc, bc, wc2, cconst);
  hipLaunchKernelGGL(k_qbase, dim3(512), dim3(256), 0, stream,
                     emb, Wfix, bfix, Wstep, bstep, qbase);
  hipLaunchKernelGGL(k_c, dim3(256), dim3(256), 0, stream,
                     emb, wc2, cconst, cvec);
  hipLaunchKernelGGL(k_gemm, dim3(1024), dim3(256), 0, stream,
                     emb, Wqkv, bqkv, Wc, bc, kk_, vv_, lk2, 6, 0b101);
  hipLaunchKernelGGL(k_roll, dim3(512), dim3(512), 0, stream,
                     emb, Wstep, kk_, vv_, lk2, qbase, cvec, out);
}

// Round 4
// 1456.565 us; speedup vs baseline: 3.2580x; 1.1372x over previous
//
#include <hip/hip_runtime.h>
#include <math.h>

// B=512, N=128, E=256, H=8, D=32. All fp32 (argmax fidelity requires it).
//
// Round-4: k_roll restructured.
//  - operand-sharing pairing: every thread computes 2 outputs sharing its LDS reads
//    (scores: n/n+64 same head; ctx: e/e+16 same head; z: n/n+64) -> LDS b128 issue halved.
//  - softmax folded into score phase (wave == head, in-wave shuffle reductions).
//  - argmax + lse fused via shifted-ref exp(lg-10); all threads derive action locally.
//  - 6 barriers/step (was 9), 2-way split accumulator chains.
//  Precompute kernels unchanged from round 3.

#define B_ 512
#define N_ 128
#define E_ 256
#define H_ 8
#define D_ 32
#define NEG (-1.0e9f)
#define CLIPV 10.0f
#define SCALE 0.17677669529663688110f  /* 1/sqrt(32), fp32-rounded */

// ---------------------------------------------------------------- K0: weight folds
__global__ void k0_prep(const float* __restrict__ Wqkv, const float* __restrict__ bqkv,
                        const float* __restrict__ Wmlp, const float* __restrict__ bmlp,
                        float* __restrict__ Wc, float* __restrict__ bc,
                        float* __restrict__ wc2, float* __restrict__ cconst) {
  int t = threadIdx.x;
  int blk = blockIdx.x;
  __shared__ float row_s[E_];
  if (blk < E_) {
    int g = blk;
    row_s[t] = Wqkv[g * 768 + 512 + t];
    __syncthreads();
    int f = t;
    const float4* wm4 = (const float4*)(Wmlp + f * E_);
    const float4* w34 = (const float4*)row_s;
    float acc = 0.f;
#pragma unroll 8
    for (int j = 0; j < E_ / 4; ++j) {
      float4 a = w34[j]; float4 bv = wm4[j];
      acc += a.x * bv.x + a.y * bv.y + a.z * bv.z + a.w * bv.w;
    }
    Wc[g * E_ + f] = acc;
  } else {
    int f = t;
    float a1 = 0.f, a2 = 0.f;
    for (int e = 0; e < E_; ++e) {
      a1 += bqkv[512 + e] * Wmlp[f * E_ + e];
      a2 += Wqkv[f * 768 + 512 + e] * bmlp[e];
    }
    bc[f] = a1;
    wc2[f] = a2;
    if (t == 0) {
      float c = 0.f;
      for (int e = 0; e < E_; ++e) c += bqkv[512 + e] * bmlp[e];
      *cconst = c;
    }
  }
}

// ---------------------------------------------------------------- K1: precompute GEMM (3 tensors)
__global__ __launch_bounds__(256, 2)
void k_gemm(const float* __restrict__ emb, const float* __restrict__ Wqkv,
            const float* __restrict__ bqkv,
            const float* __restrict__ Wc, const float* __restrict__ bc,
            float* __restrict__ kk_, float* __restrict__ vv_,
            float* __restrict__ lk2, int ncc, int tmask) {
  __shared__ float As[256 * 64];  // [kk][m], exactly 64 KiB
  int t = threadIdx.x;
  int r0 = blockIdx.x * 64;
  {
    int m = t >> 2;
    int c0 = t & 3;
    const float4* e4 = (const float4*)emb;
#pragma unroll
    for (int p = 0; p < 16; ++p) {
      int c4 = c0 + p * 4;
      float4 a = e4[(size_t)(r0 + m) * 64 + c4];
      As[(c4 * 4 + 0) * 64 + m] = a.x;
      As[(c4 * 4 + 1) * 64 + m] = a.y;
      As[(c4 * 4 + 2) * 64 + m] = a.z;
      As[(c4 * 4 + 3) * 64 + m] = a.w;
    }
  }
  __syncthreads();
  int tx = t & 15, ty = t >> 4;
  const float4* As4 = (const float4*)As;
  for (int cc = 0; cc < ncc; ++cc) {
    const float* Bp; int ldb4; const float* bias; float* outp;
    int colbase = (cc & 1) * 128;
    switch (cc >> 1) {
      case 0:  Bp = Wqkv + colbase;          ldb4 = 192; bias = bqkv + colbase;       outp = kk_; break;
      case 1:  Bp = Wqkv + 256 + colbase;    ldb4 = 192; bias = bqkv + 256 + colbase; outp = vv_; break;
      default: Bp = Wc + colbase;            ldb4 = 64;  bias = bc + colbase;         outp = lk2; break;
    }
    const float4* B4 = (const float4*)Bp;
    float acc[4][8];
#pragma unroll
    for (int i = 0; i < 4; ++i)
#pragma unroll
      for (int j = 0; j < 8; ++j) acc[i][j] = 0.f;

#pragma unroll 4
    for (int kk = 0; kk < 256; ++kk) {
      float4 b0 = B4[kk * ldb4 + tx * 2];
      float4 b1 = B4[kk * ldb4 + tx * 2 + 1];
      float4 av = As4[kk * 16 + ty];
      float a_[4] = {av.x, av.y, av.z, av.w};
#pragma unroll
      for (int i = 0; i < 4; ++i) {
        acc[i][0] += a_[i] * b0.x; acc[i][1] += a_[i] * b0.y;
        acc[i][2] += a_[i] * b0.z; acc[i][3] += a_[i] * b0.w;
        acc[i][4] += a_[i] * b1.x; acc[i][5] += a_[i] * b1.y;
        acc[i][6] += a_[i] * b1.z; acc[i][7] += a_[i] * b1.w;
      }
    }
    float bj[8];
#pragma unroll
    for (int j = 0; j < 8; ++j) bj[j] = bias ? bias[tx * 8 + j] : 0.f;
    int tr = (tmask >> (cc >> 1)) & 1;
    if (!tr) {
#pragma unroll
      for (int i = 0; i < 4; ++i) {
        int row = r0 + ty * 4 + i;
        float4 o0 = make_float4(acc[i][0] + bj[0], acc[i][1] + bj[1], acc[i][2] + bj[2], acc[i][3] + bj[3]);
        float4 o1 = make_float4(acc[i][4] + bj[4], acc[i][5] + bj[5], acc[i][6] + bj[6], acc[i][7] + bj[7]);
        float4* o4 = (float4*)(outp + (size_t)row * 256 + colbase + tx * 8);
        o4[0] = o0; o4[1] = o1;
      }
    } else {
#pragma unroll
      for (int i = 0; i < 4; ++i) {
        int row = r0 + ty * 4 + i;
        int bb = row >> 7, nn = row & 127;
        float* op = outp + (size_t)bb * 32768 + nn;
#pragma unroll
        for (int j = 0; j < 8; ++j)
          op[(size_t)(colbase + tx * 8 + j) * 128] = acc[i][j] + bj[j];
      }
    }
  }
}

// ---------------------------------------------------------------- K2: qbase per b
__global__ void k_qbase(const float* __restrict__ emb, const float* __restrict__ Wfix,
                        const float* __restrict__ bfix, const float* __restrict__ Wstep,
                        const float* __restrict__ bstep, float* __restrict__ qbase) {
  int b = blockIdx.x, t = threadIdx.x;
  __shared__ float ge[E_], fi[E_];
  const float* eb = emb + (size_t)b * N_ * E_;
  float s = 0.f;
#pragma unroll 8
  for (int n = 0; n < N_; ++n) s += eb[n * E_ + t];
  ge[t] = s * (1.0f / 128.0f);
  fi[t] = eb[t];
  __syncthreads();
  float acc = bfix[t] + bstep[t];
#pragma unroll 4
  for (int g = 0; g < E_; ++g)
    acc += ge[g] * Wfix[g * E_ + t] + fi[g] * Wstep[g * E_ + t];
  qbase[b * E_ + t] = acc;
}

// ---------------------------------------------------------------- K3: c[b,n]
__global__ void k_c(const float* __restrict__ emb, const float* __restrict__ wc2,
                    const float* __restrict__ cconst, float* __restrict__ cvec) {
  __shared__ float w[E_];
  int t = threadIdx.x;
  w[t] = wc2[t];
  __syncthreads();
  int row = blockIdx.x * 256 + t;
  const float4* e4 = (const float4*)(emb + (size_t)row * E_);
  const float4* w4 = (const float4*)w;
  float acc = 0.f;
#pragma unroll 8
  for (int j = 0; j < E_ / 4; ++j) {
    float4 a = e4[j], bv = w4[j];
    acc += a.x * bv.x + a.y * bv.y + a.z * bv.z + a.w * bv.w;
  }
  cvec[row] = acc + *cconst;
}

// ---------------------------------------------------------------- K4: register-resident rollout
// One block (512 thr, 8 waves) per batch element.
// Work buffer layout (floats): q_s[256] | at_s[8*132] | pctx[4*256] | ctx_s[256] | zq[8*128]
#define QS_OFF   0
#define AT_OFF   256
#define PCT_OFF  1312
#define CTX_OFF  2336
#define ZQ_OFF   2592

__global__ __launch_bounds__(512, 2)
void k_roll(const float* __restrict__ emb, const float* __restrict__ Wstep,
            const float* __restrict__ kT, const float* __restrict__ vv_,
            const float* __restrict__ lkT,
            const float* __restrict__ qbase, const float* __restrict__ cvec,
            float* __restrict__ out) {
  int lt = threadIdx.x;
  int b = blockIdx.x;

  __shared__ float sq_lds[128 * 260];   // 130 KiB
  __shared__ float work[6144];          // 24 KiB (init GEMM staging / roll buffers)
  __shared__ int   vis[128];
  __shared__ float zredv[2];
  __shared__ int   zredi[2];
  __shared__ float sred[2];

  if (lt < 128) vis[lt] = (lt == 0) ? 1 : 0;

  // ---- init phase A: sq[n][e] = sum_g emb[b][n][g] * Wstep[(256+g)*256+e] ----
  {
    float* At = work;           // [16][128]
    float* Bs = work + 2048;    // [16][256]
    const float4* eb4 = (const float4*)(emb + (size_t)b * 32768);
    const float* W2 = Wstep + 65536;
    int n0 = (lt & 31) * 4;
    int e0 = (lt >> 5) * 16;
    float acc[4][16];
#pragma unroll
    for (int i = 0; i < 4; ++i)
#pragma unroll
      for (int j = 0; j < 16; ++j) acc[i][j] = 0.f;

    for (int gc = 0; gc < 16; ++gc) {
      {
        int n = lt & 127, q4g = lt >> 7;
        float4 a = eb4[n * 64 + gc * 4 + q4g];
        At[(q4g * 4 + 0) * 128 + n] = a.x;
        At[(q4g * 4 + 1) * 128 + n] = a.y;
        At[(q4g * 4 + 2) * 128 + n] = a.z;
        At[(q4g * 4 + 3) * 128 + n] = a.w;
      }
      {
        const float4* w4 = (const float4*)(W2 + gc * 16 * 256);
        ((float4*)Bs)[lt] = w4[lt];
        ((float4*)Bs)[lt + 512] = w4[lt + 512];
      }
      __syncthreads();
#pragma unroll
      for (int gi = 0; gi < 16; ++gi) {
        float4 a4 = *(const float4*)(At + gi * 128 + n0);
        const float4* bp = (const float4*)(Bs + gi * 256 + e0);
        float4 b0 = bp[0], b1 = bp[1], b2 = bp[2], b3 = bp[3];
        float av[4] = {a4.x, a4.y, a4.z, a4.w};
        float bv[16] = {b0.x, b0.y, b0.z, b0.w, b1.x, b1.y, b1.z, b1.w,
                        b2.x, b2.y, b2.z, b2.w, b3.x, b3.y, b3.z, b3.w};
#pragma unroll
        for (int i = 0; i < 4; ++i)
#pragma unroll
          for (int j = 0; j < 16; ++j) acc[i][j] += av[i] * bv[j];
      }
      __syncthreads();
    }
#pragma unroll
    for (int i = 0; i < 4; ++i)
#pragma unroll
      for (int j4 = 0; j4 < 4; ++j4)
        *(float4*)(sq_lds + (n0 + i) * 260 + e0 + j4 * 4) =
            make_float4(acc[i][j4 * 4], acc[i][j4 * 4 + 1], acc[i][j4 * 4 + 2], acc[i][j4 * 4 + 3]);
  }

  // ---- init phase B: register fills (coalesced / near-coalesced) ----
  const float* kTb = kT + (size_t)b * 32768;
  const float* vb  = vv_ + (size_t)b * 32768;
  const float* lTb = lkT + (size_t)b * 32768;

  // scores mapping: h = lt>>6 (wave == head), j = lt&63; outputs n in {j, j+64}
  int sh = lt >> 6, sj = lt & 63;
  // ctx mapping: ep = lt&127, nq = lt>>7; h2 = ep>>4, e0i = h2*32 + (ep&15); outputs {e0i, e0i+16}
  int ep = lt & 127, nq = lt >> 7;
  int h2 = ep >> 4, e0i = h2 * 32 + (ep & 15);
  // z mapping: zr = lt&63, es = lt>>6; outputs n in {zr, zr+64}, e-range [es*32, es*32+32)
  int zr = lt & 63, es = lt >> 6;

  float k_reg[2][32];
#pragma unroll
  for (int c = 0; c < 2; ++c)
#pragma unroll
    for (int d = 0; d < 32; ++d)
      k_reg[c][d] = kTb[(sh * 32 + d) * 128 + sj + c * 64];

  float v_reg[2][32];
#pragma unroll
  for (int c = 0; c < 2; ++c)
#pragma unroll
    for (int m = 0; m < 32; ++m)
      v_reg[c][m] = vb[(nq * 32 + m) * 256 + e0i + c * 16];

  float l_reg[2][32];
#pragma unroll
  for (int c = 0; c < 2; ++c)
#pragma unroll
    for (int m = 0; m < 32; ++m)
      l_reg[c][m] = lTb[(es * 32 + m) * 128 + zr + c * 64];

  float qb_r = (lt < 256) ? qbase[b * 256 + lt] : 0.f;
  float cb_r = (lt < 128) ? cvec[b * 128 + lt] : 0.f;
  float lp = 0.f;
  int cur = 0;
  __syncthreads();

  float* q_s   = work + QS_OFF;
  float* at_s  = work + AT_OFF;   // stride 132 per head (bank-conflict pad)
  float* pctx  = work + PCT_OFF;  // [4][256]
  float* ctx_s = work + CTX_OFF;
  float* zq    = work + ZQ_OFF;   // [8][128]

#pragma unroll 1
  for (int it = 0; it < N_ - 1; ++it) {
    // --- consume previous step's reduction; build q; update vis ---
    if (it) {
      float v0 = zredv[0], v1 = zredv[1];
      int i0 = zredi[0], i1 = zredi[1];
      float vmax;
      if (v1 > v0 || (v1 == v0 && i1 < i0)) { cur = i1; vmax = v1; }
      else                                  { cur = i0; vmax = v0; }
      if (lt == cur) vis[cur] = 1;
      if (lt == 0) lp += CLIPV * tanhf(vmax * SCALE) - 10.0f - logf(sred[0] + sred[1]);
    }
    if (lt < 256) q_s[lt] = qb_r + sq_lds[cur * 260 + lt];
    __syncthreads();

    // --- scores + softmax (wave == head) ---
    {
      const float4* q4 = (const float4*)(q_s + sh * 32);
      float s0a = 0.f, s0b = 0.f, s1a = 0.f, s1b = 0.f;
#pragma unroll
      for (int dd = 0; dd < 8; ++dd) {
        float4 qv = q4[dd];
        if (dd & 1) {
          s0b += qv.x * k_reg[0][dd * 4] + qv.y * k_reg[0][dd * 4 + 1]
               + qv.z * k_reg[0][dd * 4 + 2] + qv.w * k_reg[0][dd * 4 + 3];
          s1b += qv.x * k_reg[1][dd * 4] + qv.y * k_reg[1][dd * 4 + 1]
               + qv.z * k_reg[1][dd * 4 + 2] + qv.w * k_reg[1][dd * 4 + 3];
        } else {
          s0a += qv.x * k_reg[0][dd * 4] + qv.y * k_reg[0][dd * 4 + 1]
               + qv.z * k_reg[0][dd * 4 + 2] + qv.w * k_reg[0][dd * 4 + 3];
          s1a += qv.x * k_reg[1][dd * 4] + qv.y * k_reg[1][dd * 4 + 1]
               + qv.z * k_reg[1][dd * 4 + 2] + qv.w * k_reg[1][dd * 4 + 3];
        }
      }
      float sc0 = vis[sj]      ? NEG : (s0a + s0b) * SCALE;
      float sc1 = vis[sj + 64] ? NEG : (s1a + s1b) * SCALE;
      float m = fmaxf(sc0, sc1);
#pragma unroll
      for (int o = 32; o > 0; o >>= 1) m = fmaxf(m, __shfl_xor(m, o));
      float e0 = expf(sc0 - m), e1 = expf(sc1 - m);
      float ss = e0 + e1;
#pragma unroll
      for (int o = 32; o > 0; o >>= 1) ss += __shfl_xor(ss, o);
      float inv = 1.0f / ss;
      at_s[sh * 132 + sj] = e0 * inv;
      at_s[sh * 132 + sj + 64] = e1 * inv;
    }
    __syncthreads();

    // --- ctx partial: thread owns (e0i, e0i+16), n-range [nq*32, +32) ---
    {
      const float4* a4 = (const float4*)(at_s + h2 * 132 + nq * 32);
      float c0a = 0.f, c0b = 0.f, c1a = 0.f, c1b = 0.f;
#pragma unroll
      for (int jj = 0; jj < 8; ++jj) {
        float4 av = a4[jj];
        if (jj & 1) {
          c0b += av.x * v_reg[0][jj * 4] + av.y * v_reg[0][jj * 4 + 1]
               + av.z * v_reg[0][jj * 4 + 2] + av.w * v_reg[0][jj * 4 + 3];
          c1b += av.x * v_reg[1][jj * 4] + av.y * v_reg[1][jj * 4 + 1]
               + av.z * v_reg[1][jj * 4 + 2] + av.w * v_reg[1][jj * 4 + 3];
        } else {
          c0a += av.x * v_reg[0][jj * 4] + av.y * v_reg[0][jj * 4 + 1]
               + av.z * v_reg[0][jj * 4 + 2] + av.w * v_reg[0][jj * 4 + 3];
          c1a += av.x * v_reg[1][jj * 4] + av.y * v_reg[1][jj * 4 + 1]
               + av.z * v_reg[1][jj * 4 + 2] + av.w * v_reg[1][jj * 4 + 3];
        }
      }
      pctx[nq * 256 + e0i] = c0a + c0b;
      pctx[nq * 256 + e0i + 16] = c1a + c1b;
    }
    __syncthreads();
    if (lt < 256)
      ctx_s[lt] = (pctx[lt] + pctx[lt + 256]) + (pctx[lt + 512] + pctx[lt + 768]);
    __syncthreads();

    // --- z partial: thread owns (zr, zr+64), e-range [es*32, +32) ---
    {
      const float4* c4 = (const float4*)(ctx_s + es * 32);
      float z0a = 0.f, z0b = 0.f, z1a = 0.f, z1b = 0.f;
#pragma unroll
      for (int jj = 0; jj < 8; ++jj) {
        float4 cv = c4[jj];
        if (jj & 1) {
          z0b += cv.x * l_reg[0][jj * 4] + cv.y * l_reg[0][jj * 4 + 1]
               + cv.z * l_reg[0][jj * 4 + 2] + cv.w * l_reg[0][jj * 4 + 3];
          z1b += cv.x * l_reg[1][jj * 4] + cv.y * l_reg[1][jj * 4 + 1]
               + cv.z * l_reg[1][jj * 4 + 2] + cv.w * l_reg[1][jj * 4 + 3];
        } else {
          z0a += cv.x * l_reg[0][jj * 4] + cv.y * l_reg[0][jj * 4 + 1]
               + cv.z * l_reg[0][jj * 4 + 2] + cv.w * l_reg[0][jj * 4 + 3];
          z1a += cv.x * l_reg[1][jj * 4] + cv.y * l_reg[1][jj * 4 + 1]
               + cv.z * l_reg[1][jj * 4 + 2] + cv.w * l_reg[1][jj * 4 + 3];
        }
      }
      zq[es * 128 + zr] = z0a + z0b;
      zq[es * 128 + zr + 64] = z1a + z1b;
    }
    __syncthreads();

    // --- z assemble + argmax + shifted-lse (2 waves) ---
    if (lt < 128) {
      float zv = ((zq[lt] + zq[lt + 128]) + (zq[lt + 256] + zq[lt + 384]))
               + ((zq[lt + 512] + zq[lt + 640]) + (zq[lt + 768] + zq[lt + 896])) + cb_r;
      int visd = vis[lt];
      float val = visd ? -1e30f : zv;
      int idx = lt;
      float tsum = visd ? 0.f : expf(CLIPV * tanhf(zv * SCALE) - 10.0f);
#pragma unroll
      for (int o = 32; o > 0; o >>= 1) {
        float ov = __shfl_xor(val, o);
        int oi = __shfl_xor(idx, o);
        tsum += __shfl_xor(tsum, o);
        if (ov > val || (ov == val && oi < idx)) { val = ov; idx = oi; }
      }
      int wv = lt >> 6;
      if ((lt & 63) == 0) { zredv[wv] = val; zredi[wv] = idx; sred[wv] = tsum; }
    }
    __syncthreads();
  }

  // consume final step's production
  if (lt == 0) {
    float v0 = zredv[0], v1 = zredv[1];
    int i0 = zredi[0], i1 = zredi[1];
    float vmax = (v1 > v0 || (v1 == v0 && i1 < i0)) ? v1 : v0;
    lp += CLIPV * tanhf(vmax * SCALE) - 10.0f - logf(sred[0] + sred[1]);
    out[b] = lp;
  }
}

// ---------------------------------------------------------------- launch
extern "C" void kernel_launch(void* const* d_in, const int* in_sizes, int n_in,
                              void* d_out, int out_size, void* d_ws, size_t ws_size,
                              hipStream_t stream) {
  (void)in_sizes; (void)n_in; (void)out_size; (void)ws_size;
  const float* emb   = (const float*)d_in[0];
  const float* Wqkv  = (const float*)d_in[1];
  const float* bqkv  = (const float*)d_in[2];
  const float* Wfix  = (const float*)d_in[3];
  const float* bfix  = (const float*)d_in[4];
  const float* Wstep = (const float*)d_in[5];
  const float* bstep = (const float*)d_in[6];
  const float* Wmlp  = (const float*)d_in[7];
  const float* bmlp  = (const float*)d_in[8];
  float* out = (float*)d_out;
  float* ws = (float*)d_ws;

  const size_t NBE = (size_t)B_ * N_ * E_;  // 16,777,216 floats
  float* kk_    = ws;                  // kT
  float* vv_    = ws + NBE;            // v
  float* lk2    = ws + 2 * NBE;        // lkT
  float* qbase  = ws + 3 * NBE;        // 131072
  float* cvec   = qbase + 131072;      // 65536
  float* Wc     = cvec + 65536;        // 65536
  float* bc     = Wc + 65536;          // 256
  float* wc2    = bc + 256;            // 256
  float* cconst = wc2 + 256;           // (64 pad)

  hipLaunchKernelGGL(k0_prep, dim3(257), dim3(256), 0, stream,
                     Wqkv, bqkv, Wmlp, bmlp, Wc, bc, wc2, cconst);
  hipLaunchKernelGGL(k_qbase, dim3(512), dim3(256), 0, stream,
                     emb, Wfix, bfix, Wstep, bstep, qbase);
  hipLaunchKernelGGL(k_c, dim3(256), dim3(256), 0, stream,
                     emb, wc2, cconst, cvec);
  hipLaunchKernelGGL(k_gemm, dim3(1024), dim3(256), 0, stream,
                     emb, Wqkv, bqkv, Wc, bc, kk_, vv_, lk2, 6, 0b101);
  hipLaunchKernelGGL(k_roll, dim3(512), dim3(512), 0, stream,
                     emb, Wstep, kk_, vv_, lk2, qbase, cvec, out);
}

// Round 5
// 1373.355 us; speedup vs baseline: 3.4554x; 1.0606x over previous
//
#include <hip/hip_runtime.h>
#include <math.h>

// B=512, N=128, E=256, H=8, D=32. All fp32 (argmax fidelity requires it).
//
// Round-5: wave-per-head rollout, 1 barrier per step.
//  - wave h owns head h: scores -> softmax -> ctx[h-slice] -> zpart[h] all wave-local
//    (wave-private LDS slices, no __syncthreads between phases).
//  - one barrier after zpart writes; phase C (argmax+lse) computed redundantly by all
//    8 waves; zp double-buffered; vis/cur/lp in registers.
//  - reductions: DPP (quad_perm/row_ror) + 2 shuffles instead of 6-level shfl chains;
//    argmax via exact ballot-ffs tiebreak (== reference first-index semantics).
//  - softmax division deferred to ctx scaling (sum-reduce off critical path).
//  - qbase folded into sq_lds at init. Precompute kernels unchanged.

#define B_ 512
#define N_ 128
#define E_ 256
#define H_ 8
#define D_ 32
#define NEG (-1.0e9f)
#define CLIPV 10.0f
#define SCALE 0.17677669529663688110f  /* 1/sqrt(32), fp32-rounded */

// ---------------- wave-wide reductions (64 lanes) ----------------
template <int CTRL>
__device__ __forceinline__ float dpp_f(float x) {
  int r = __builtin_amdgcn_update_dpp(__float_as_int(x), __float_as_int(x),
                                      CTRL, 0xf, 0xf, false);
  return __int_as_float(r);
}
__device__ __forceinline__ float wred_max(float v) {
  v = fmaxf(v, dpp_f<0xB1>(v));    // quad_perm(1,0,3,2)  : xor 1
  v = fmaxf(v, dpp_f<0x4E>(v));    // quad_perm(2,3,0,1)  : xor 2
  v = fmaxf(v, dpp_f<0x124>(v));   // row_ror:4
  v = fmaxf(v, dpp_f<0x128>(v));   // row_ror:8
  v = fmaxf(v, __shfl_xor(v, 16));
  v = fmaxf(v, __shfl_xor(v, 32));
  return v;
}
__device__ __forceinline__ float wred_sum(float v) {
  v += dpp_f<0xB1>(v);
  v += dpp_f<0x4E>(v);
  v += dpp_f<0x124>(v);
  v += dpp_f<0x128>(v);
  v += __shfl_xor(v, 16);
  v += __shfl_xor(v, 32);
  return v;
}

// ---------------------------------------------------------------- K0: weight folds
__global__ void k0_prep(const float* __restrict__ Wqkv, const float* __restrict__ bqkv,
                        const float* __restrict__ Wmlp, const float* __restrict__ bmlp,
                        float* __restrict__ Wc, float* __restrict__ bc,
                        float* __restrict__ wc2, float* __restrict__ cconst) {
  int t = threadIdx.x;
  int blk = blockIdx.x;
  __shared__ float row_s[E_];
  if (blk < E_) {
    int g = blk;
    row_s[t] = Wqkv[g * 768 + 512 + t];
    __syncthreads();
    int f = t;
    const float4* wm4 = (const float4*)(Wmlp + f * E_);
    const float4* w34 = (const float4*)row_s;
    float acc = 0.f;
#pragma unroll 8
    for (int j = 0; j < E_ / 4; ++j) {
      float4 a = w34[j]; float4 bv = wm4[j];
      acc += a.x * bv.x + a.y * bv.y + a.z * bv.z + a.w * bv.w;
    }
    Wc[g * E_ + f] = acc;
  } else {
    int f = t;
    float a1 = 0.f, a2 = 0.f;
    for (int e = 0; e < E_; ++e) {
      a1 += bqkv[512 + e] * Wmlp[f * E_ + e];
      a2 += Wqkv[f * 768 + 512 + e] * bmlp[e];
    }
    bc[f] = a1;
    wc2[f] = a2;
    if (t == 0) {
      float c = 0.f;
      for (int e = 0; e < E_; ++e) c += bqkv[512 + e] * bmlp[e];
      *cconst = c;
    }
  }
}

// ---------------------------------------------------------------- K1: precompute GEMM (3 tensors)
__global__ __launch_bounds__(256, 2)
void k_gemm(const float* __restrict__ emb, const float* __restrict__ Wqkv,
            const float* __restrict__ bqkv,
            const float* __restrict__ Wc, const float* __restrict__ bc,
            float* __restrict__ kk_, float* __restrict__ vv_,
            float* __restrict__ lk2, int ncc, int tmask) {
  __shared__ float As[256 * 64];  // [kk][m], exactly 64 KiB
  int t = threadIdx.x;
  int r0 = blockIdx.x * 64;
  {
    int m = t >> 2;
    int c0 = t & 3;
    const float4* e4 = (const float4*)emb;
#pragma unroll
    for (int p = 0; p < 16; ++p) {
      int c4 = c0 + p * 4;
      float4 a = e4[(size_t)(r0 + m) * 64 + c4];
      As[(c4 * 4 + 0) * 64 + m] = a.x;
      As[(c4 * 4 + 1) * 64 + m] = a.y;
      As[(c4 * 4 + 2) * 64 + m] = a.z;
      As[(c4 * 4 + 3) * 64 + m] = a.w;
    }
  }
  __syncthreads();
  int tx = t & 15, ty = t >> 4;
  const float4* As4 = (const float4*)As;
  for (int cc = 0; cc < ncc; ++cc) {
    const float* Bp; int ldb4; const float* bias; float* outp;
    int colbase = (cc & 1) * 128;
    switch (cc >> 1) {
      case 0:  Bp = Wqkv + colbase;          ldb4 = 192; bias = bqkv + colbase;       outp = kk_; break;
      case 1:  Bp = Wqkv + 256 + colbase;    ldb4 = 192; bias = bqkv + 256 + colbase; outp = vv_; break;
      default: Bp = Wc + colbase;            ldb4 = 64;  bias = bc + colbase;         outp = lk2; break;
    }
    const float4* B4 = (const float4*)Bp;
    float acc[4][8];
#pragma unroll
    for (int i = 0; i < 4; ++i)
#pragma unroll
      for (int j = 0; j < 8; ++j) acc[i][j] = 0.f;

#pragma unroll 4
    for (int kk = 0; kk < 256; ++kk) {
      float4 b0 = B4[kk * ldb4 + tx * 2];
      float4 b1 = B4[kk * ldb4 + tx * 2 + 1];
      float4 av = As4[kk * 16 + ty];
      float a_[4] = {av.x, av.y, av.z, av.w};
#pragma unroll
      for (int i = 0; i < 4; ++i) {
        acc[i][0] += a_[i] * b0.x; acc[i][1] += a_[i] * b0.y;
        acc[i][2] += a_[i] * b0.z; acc[i][3] += a_[i] * b0.w;
        acc[i][4] += a_[i] * b1.x; acc[i][5] += a_[i] * b1.y;
        acc[i][6] += a_[i] * b1.z; acc[i][7] += a_[i] * b1.w;
      }
    }
    float bj[8];
#pragma unroll
    for (int j = 0; j < 8; ++j) bj[j] = bias ? bias[tx * 8 + j] : 0.f;
    int tr = (tmask >> (cc >> 1)) & 1;
    if (!tr) {
#pragma unroll
      for (int i = 0; i < 4; ++i) {
        int row = r0 + ty * 4 + i;
        float4 o0 = make_float4(acc[i][0] + bj[0], acc[i][1] + bj[1], acc[i][2] + bj[2], acc[i][3] + bj[3]);
        float4 o1 = make_float4(acc[i][4] + bj[4], acc[i][5] + bj[5], acc[i][6] + bj[6], acc[i][7] + bj[7]);
        float4* o4 = (float4*)(outp + (size_t)row * 256 + colbase + tx * 8);
        o4[0] = o0; o4[1] = o1;
      }
    } else {
#pragma unroll
      for (int i = 0; i < 4; ++i) {
        int row = r0 + ty * 4 + i;
        int bb = row >> 7, nn = row & 127;
        float* op = outp + (size_t)bb * 32768 + nn;
#pragma unroll
        for (int j = 0; j < 8; ++j)
          op[(size_t)(colbase + tx * 8 + j) * 128] = acc[i][j] + bj[j];
      }
    }
  }
}

// ---------------------------------------------------------------- K2: qbase per b
__global__ void k_qbase(const float* __restrict__ emb, const float* __restrict__ Wfix,
                        const float* __restrict__ bfix, const float* __restrict__ Wstep,
                        const float* __restrict__ bstep, float* __restrict__ qbase) {
  int b = blockIdx.x, t = threadIdx.x;
  __shared__ float ge[E_], fi[E_];
  const float* eb = emb + (size_t)b * N_ * E_;
  float s = 0.f;
#pragma unroll 8
  for (int n = 0; n < N_; ++n) s += eb[n * E_ + t];
  ge[t] = s * (1.0f / 128.0f);
  fi[t] = eb[t];
  __syncthreads();
  float acc = bfix[t] + bstep[t];
#pragma unroll 4
  for (int g = 0; g < E_; ++g)
    acc += ge[g] * Wfix[g * E_ + t] + fi[g] * Wstep[g * E_ + t];
  qbase[b * E_ + t] = acc;
}

// ---------------------------------------------------------------- K3: c[b,n]
__global__ void k_c(const float* __restrict__ emb, const float* __restrict__ wc2,
                    const float* __restrict__ cconst, float* __restrict__ cvec) {
  __shared__ float w[E_];
  int t = threadIdx.x;
  w[t] = wc2[t];
  __syncthreads();
  int row = blockIdx.x * 256 + t;
  const float4* e4 = (const float4*)(emb + (size_t)row * E_);
  const float4* w4 = (const float4*)w;
  float acc = 0.f;
#pragma unroll 8
  for (int j = 0; j < E_ / 4; ++j) {
    float4 a = e4[j], bv = w4[j];
    acc += a.x * bv.x + a.y * bv.y + a.z * bv.z + a.w * bv.w;
  }
  cvec[row] = acc + *cconst;
}

// ---------------------------------------------------------------- K4: wave-per-head rollout
// One block (512 thr, 8 waves) per batch element. Wave h == head h.
// LDS: sq_lds[128][260] (q rows, qbase folded in) + work overlay.
__global__ __launch_bounds__(512, 2)
void k_roll(const float* __restrict__ emb, const float* __restrict__ Wstep,
            const float* __restrict__ kT, const float* __restrict__ vv_,
            const float* __restrict__ lkT,
            const float* __restrict__ qbase, const float* __restrict__ cvec,
            float* __restrict__ out) {
  int lt = threadIdx.x;
  int b = blockIdx.x;
  int h = lt >> 6;      // wave = head
  int j = lt & 63;      // lane

  __shared__ float sq_lds[128 * 260];   // 130 KiB (stride 260: init-store bank spread)
  __shared__ float work[6144];          // 24 KiB overlay: init At/Bs | at_s/ctx_s/zp
  float* at_s  = work;                  // [8][128] wave-private slices
  float* ctx_s = work + 1024;           // [8][32]  wave-private slices
  float* zp    = work + 1280;           // [2][8][128] double-buffered

  // ---- init: sq_lds[n][e] = qbase[b][e] + sum_g emb[b][n][g] * Wstep[256+g][e]
  {
    float* At = work;           // [16][128]
    float* Bs = work + 2048;    // [16][256]
    const float4* eb4 = (const float4*)(emb + (size_t)b * 32768);
    const float* W2 = Wstep + 65536;
    int n0 = (lt & 31) * 4;
    int e0 = (lt >> 5) * 16;
    float acc[4][16];
#pragma unroll
    for (int i = 0; i < 4; ++i)
#pragma unroll
      for (int jj = 0; jj < 16; ++jj) acc[i][jj] = 0.f;

    for (int gc = 0; gc < 16; ++gc) {
      {
        int n = lt & 127, q4g = lt >> 7;
        float4 a = eb4[n * 64 + gc * 4 + q4g];
        At[(q4g * 4 + 0) * 128 + n] = a.x;
        At[(q4g * 4 + 1) * 128 + n] = a.y;
        At[(q4g * 4 + 2) * 128 + n] = a.z;
        At[(q4g * 4 + 3) * 128 + n] = a.w;
      }
      {
        const float4* w4 = (const float4*)(W2 + gc * 16 * 256);
        ((float4*)Bs)[lt] = w4[lt];
        ((float4*)Bs)[lt + 512] = w4[lt + 512];
      }
      __syncthreads();
#pragma unroll
      for (int gi = 0; gi < 16; ++gi) {
        float4 a4 = *(const float4*)(At + gi * 128 + n0);
        const float4* bp = (const float4*)(Bs + gi * 256 + e0);
        float4 b0 = bp[0], b1 = bp[1], b2 = bp[2], b3 = bp[3];
        float av[4] = {a4.x, a4.y, a4.z, a4.w};
        float bv[16] = {b0.x, b0.y, b0.z, b0.w, b1.x, b1.y, b1.z, b1.w,
                        b2.x, b2.y, b2.z, b2.w, b3.x, b3.y, b3.z, b3.w};
#pragma unroll
        for (int i = 0; i < 4; ++i)
#pragma unroll
          for (int jj = 0; jj < 16; ++jj) acc[i][jj] += av[i] * bv[jj];
      }
      __syncthreads();
    }
    const float* qb = qbase + (size_t)b * 256;
    float qbr[16];
#pragma unroll
    for (int jj = 0; jj < 16; ++jj) qbr[jj] = qb[e0 + jj];
#pragma unroll
    for (int i = 0; i < 4; ++i)
#pragma unroll
      for (int jj = 0; jj < 16; ++jj)
        sq_lds[(n0 + i) * 260 + e0 + jj] = acc[i][jj] + qbr[jj];  // scalar: 2-way banks
  }
  __syncthreads();
  __builtin_amdgcn_sched_barrier(0);   // keep init acc[] live range from overlapping fills

  // ---- register fills (coalesced within 32/64-lane groups) ----
  const float* kTb = kT + (size_t)b * 32768;
  const float* vb  = vv_ + (size_t)b * 32768;
  const float* lTb = lkT + (size_t)b * 32768;

  float k0r[32], k1r[32];     // k[h][d][j], k[h][d][j+64]
#pragma unroll
  for (int d = 0; d < 32; ++d) {
    k0r[d] = kTb[(h * 32 + d) * 128 + j];
    k1r[d] = kTb[(h * 32 + d) * 128 + j + 64];
  }
  int e_own = h * 32 + (j & 31), nh = j >> 5;
  float vr[64];               // v[nh*64+m][e_own]
#pragma unroll
  for (int m = 0; m < 64; ++m) vr[m] = vb[(nh * 64 + m) * 256 + e_own];
  float l0r[32], l1r[32];     // lk2[j][h-slice], lk2[j+64][h-slice]
#pragma unroll
  for (int e = 0; e < 32; ++e) {
    l0r[e] = lTb[(h * 32 + e) * 128 + j];
    l1r[e] = lTb[(h * 32 + e) * 128 + j + 64];
  }
  float cv_lo = cvec[b * 128 + j];
  float cv_hi = cvec[b * 128 + j + 64];
  int vis_lo = (j == 0) ? 1 : 0, vis_hi = 0;
  int cur = 0;
  float lp = 0.f;

#pragma unroll 1
  for (int it = 0; it < N_ - 1; ++it) {
    // --- scores (wave-local; q row broadcast-read from sq_lds) ---
    const float4* q4 = (const float4*)(sq_lds + cur * 260 + h * 32);
    float sa0 = 0.f, sb0 = 0.f, sa1 = 0.f, sb1 = 0.f;
#pragma unroll
    for (int dd = 0; dd < 8; ++dd) {
      float4 qv = q4[dd];
      if (dd & 1) {
        sb0 += qv.x * k0r[dd * 4] + qv.y * k0r[dd * 4 + 1] + qv.z * k0r[dd * 4 + 2] + qv.w * k0r[dd * 4 + 3];
        sb1 += qv.x * k1r[dd * 4] + qv.y * k1r[dd * 4 + 1] + qv.z * k1r[dd * 4 + 2] + qv.w * k1r[dd * 4 + 3];
      } else {
        sa0 += qv.x * k0r[dd * 4] + qv.y * k0r[dd * 4 + 1] + qv.z * k0r[dd * 4 + 2] + qv.w * k0r[dd * 4 + 3];
        sa1 += qv.x * k1r[dd * 4] + qv.y * k1r[dd * 4 + 1] + qv.z * k1r[dd * 4 + 2] + qv.w * k1r[dd * 4 + 3];
      }
    }
    float slo = vis_lo ? NEG : (sa0 + sb0) * SCALE;
    float shi = vis_hi ? NEG : (sa1 + sb1) * SCALE;
    // --- softmax (in-wave; division deferred) ---
    float m = wred_max(fmaxf(slo, shi));
    float elo = expf(slo - m), ehi = expf(shi - m);
    at_s[h * 128 + j] = elo;
    at_s[h * 128 + 64 + j] = ehi;
    float inv = 1.0f / wred_sum(elo + ehi);
    // --- ctx for e_own over n-half (wave-local LDS read, no barrier) ---
    const float4* a4 = (const float4*)(at_s + h * 128 + nh * 64);
    float c0 = 0.f, c1 = 0.f;
#pragma unroll
    for (int mm = 0; mm < 16; ++mm) {
      float4 av = a4[mm];
      if (mm & 1)
        c1 += av.x * vr[mm * 4] + av.y * vr[mm * 4 + 1] + av.z * vr[mm * 4 + 2] + av.w * vr[mm * 4 + 3];
      else
        c0 += av.x * vr[mm * 4] + av.y * vr[mm * 4 + 1] + av.z * vr[mm * 4 + 2] + av.w * vr[mm * 4 + 3];
    }
    float c = c0 + c1;
    c += __shfl_xor(c, 32);     // combine n-halves (lanes j, j^32 share e_own)
    c *= inv;
    if (j < 32) ctx_s[h * 32 + j] = c;
    // --- z partial for head-slice (wave-local broadcast read) ---
    const float4* cx4 = (const float4*)(ctx_s + h * 32);
    float z0a = 0.f, z0b = 0.f, z1a = 0.f, z1b = 0.f;
#pragma unroll
    for (int ee = 0; ee < 8; ++ee) {
      float4 cv = cx4[ee];
      if (ee & 1) {
        z0b += cv.x * l0r[ee * 4] + cv.y * l0r[ee * 4 + 1] + cv.z * l0r[ee * 4 + 2] + cv.w * l0r[ee * 4 + 3];
        z1b += cv.x * l1r[ee * 4] + cv.y * l1r[ee * 4 + 1] + cv.z * l1r[ee * 4 + 2] + cv.w * l1r[ee * 4 + 3];
      } else {
        z0a += cv.x * l0r[ee * 4] + cv.y * l0r[ee * 4 + 1] + cv.z * l0r[ee * 4 + 2] + cv.w * l0r[ee * 4 + 3];
        z1a += cv.x * l1r[ee * 4] + cv.y * l1r[ee * 4 + 1] + cv.z * l1r[ee * 4 + 2] + cv.w * l1r[ee * 4 + 3];
      }
    }
    float* zpw = zp + (it & 1) * 1024;
    zpw[h * 128 + j] = z0a + z0b;
    zpw[h * 128 + 64 + j] = z1a + z1b;
    __syncthreads();   // the ONLY barrier per step

    // --- phase C: every wave redundantly assembles z, argmax (ballot tiebreak), lse ---
    float zlo = cv_lo, zhi = cv_hi;
#pragma unroll
    for (int hh = 0; hh < 8; ++hh) {
      zlo += zpw[hh * 128 + j];
      zhi += zpw[hh * 128 + 64 + j];
    }
    float zmlo = vis_lo ? -1e30f : zlo;
    float zmhi = vis_hi ? -1e30f : zhi;
    float vmax = wred_max(fmaxf(zmlo, zmhi));
    unsigned long long blo = __ballot(zmlo == vmax);
    int action;
    if (blo) action = __ffsll((unsigned long long)blo) - 1;
    else     action = 63 + __ffsll((unsigned long long)__ballot(zmhi == vmax));
    float lmax = CLIPV * tanhf(vmax * SCALE);
    float tlo = vis_lo ? 0.f : expf(CLIPV * tanhf(zlo * SCALE) - 10.0f);
    float thi = vis_hi ? 0.f : expf(CLIPV * tanhf(zhi * SCALE) - 10.0f);
    float S = wred_sum(tlo + thi);
    lp += lmax - 10.0f - logf(S);
    cur = action;
    vis_lo |= (action == j);
    vis_hi |= (action == j + 64);
  }
  if (lt == 0) out[b] = lp;
}

// ---------------------------------------------------------------- launch
extern "C" void kernel_launch(void* const* d_in, const int* in_sizes, int n_in,
                              void* d_out, int out_size, void* d_ws, size_t ws_size,
                              hipStream_t stream) {
  (void)in_sizes; (void)n_in; (void)out_size; (void)ws_size;
  const float* emb   = (const float*)d_in[0];
  const float* Wqkv  = (const float*)d_in[1];
  const float* bqkv  = (const float*)d_in[2];
  const float* Wfix  = (const float*)d_in[3];
  const float* bfix  = (const float*)d_in[4];
  const float* Wstep = (const float*)d_in[5];
  const float* bstep = (const float*)d_in[6];
  const float* Wmlp  = (const float*)d_in[7];
  const float* bmlp  = (const float*)d_in[8];
  float* out = (float*)d_out;
  float* ws = (float*)d_ws;

  const size_t NBE = (size_t)B_ * N_ * E_;  // 16,777,216 floats
  float* kk_    = ws;                  // kT
  float* vv_    = ws + NBE;            // v
  float* lk2    = ws + 2 * NBE;        // lkT
  float* qbase  = ws + 3 * NBE;        // 131072
  float* cvec   = qbase + 131072;      // 65536
  float* Wc     = cvec + 65536;        // 65536
  float* bc     = Wc + 65536;          // 256
  float* wc2    = bc + 256;            // 256
  float* cconst = wc2 + 256;           // (64 pad)

  hipLaunchKernelGGL(k0_prep, dim3(257), dim3(256), 0, stream,
                     Wqkv, bqkv, Wmlp, bmlp, Wc, bc, wc2, cconst);
  hipLaunchKernelGGL(k_qbase, dim3(512), dim3(256), 0, stream,
                     emb, Wfix, bfix, Wstep, bstep, qbase);
  hipLaunchKernelGGL(k_c, dim3(256), dim3(256), 0, stream,
                     emb, wc2, cconst, cvec);
  hipLaunchKernelGGL(k_gemm, dim3(1024), dim3(256), 0, stream,
                     emb, Wqkv, bqkv, Wc, bc, kk_, vv_, lk2, 6, 0b101);
  hipLaunchKernelGGL(k_roll, dim3(512), dim3(512), 0, stream,
                     emb, Wstep, kk_, vv_, lk2, qbase, cvec, out);
}

// Round 6
// 1369.866 us; speedup vs baseline: 3.4642x; 1.0025x over previous
//
#include <hip/hip_runtime.h>
#include <math.h>

// B=512, N=128, E=256, H=8, D=32. All fp32 (argmax fidelity requires it).
//
// Round-6: ONE change vs round 5: k_roll __launch_bounds__(512, 1).
//  R3-R5 all showed VGPR_Count=128 with 192 floats/thread of "register-resident"
//  state -> the compiler was reloading k/v/lk2 from L2 every step + spilling to
//  scratch (WRITE_SIZE 39.6MB for a 2KB-output kernel). Occupancy is LDS-capped
//  at 1 block/CU anyway, so the 128-VGPR cap was pure loss. Budget 512 VGPR/wave
//  lets the 192 data floats actually stay live across the 127-step loop.

#define B_ 512
#define N_ 128
#define E_ 256
#define H_ 8
#define D_ 32
#define NEG (-1.0e9f)
#define CLIPV 10.0f
#define SCALE 0.17677669529663688110f  /* 1/sqrt(32), fp32-rounded */

// ---------------- wave-wide reductions (64 lanes) ----------------
template <int CTRL>
__device__ __forceinline__ float dpp_f(float x) {
  int r = __builtin_amdgcn_update_dpp(__float_as_int(x), __float_as_int(x),
                                      CTRL, 0xf, 0xf, false);
  return __int_as_float(r);
}
__device__ __forceinline__ float wred_max(float v) {
  v = fmaxf(v, dpp_f<0xB1>(v));    // quad_perm(1,0,3,2)  : xor 1
  v = fmaxf(v, dpp_f<0x4E>(v));    // quad_perm(2,3,0,1)  : xor 2
  v = fmaxf(v, dpp_f<0x124>(v));   // row_ror:4
  v = fmaxf(v, dpp_f<0x128>(v));   // row_ror:8
  v = fmaxf(v, __shfl_xor(v, 16));
  v = fmaxf(v, __shfl_xor(v, 32));
  return v;
}
__device__ __forceinline__ float wred_sum(float v) {
  v += dpp_f<0xB1>(v);
  v += dpp_f<0x4E>(v);
  v += dpp_f<0x124>(v);
  v += dpp_f<0x128>(v);
  v += __shfl_xor(v, 16);
  v += __shfl_xor(v, 32);
  return v;
}

// ---------------------------------------------------------------- K0: weight folds
__global__ void k0_prep(const float* __restrict__ Wqkv, const float* __restrict__ bqkv,
                        const float* __restrict__ Wmlp, const float* __restrict__ bmlp,
                        float* __restrict__ Wc, float* __restrict__ bc,
                        float* __restrict__ wc2, float* __restrict__ cconst) {
  int t = threadIdx.x;
  int blk = blockIdx.x;
  __shared__ float row_s[E_];
  if (blk < E_) {
    int g = blk;
    row_s[t] = Wqkv[g * 768 + 512 + t];
    __syncthreads();
    int f = t;
    const float4* wm4 = (const float4*)(Wmlp + f * E_);
    const float4* w34 = (const float4*)row_s;
    float acc = 0.f;
#pragma unroll 8
    for (int j = 0; j < E_ / 4; ++j) {
      float4 a = w34[j]; float4 bv = wm4[j];
      acc += a.x * bv.x + a.y * bv.y + a.z * bv.z + a.w * bv.w;
    }
    Wc[g * E_ + f] = acc;
  } else {
    int f = t;
    float a1 = 0.f, a2 = 0.f;
    for (int e = 0; e < E_; ++e) {
      a1 += bqkv[512 + e] * Wmlp[f * E_ + e];
      a2 += Wqkv[f * 768 + 512 + e] * bmlp[e];
    }
    bc[f] = a1;
    wc2[f] = a2;
    if (t == 0) {
      float c = 0.f;
      for (int e = 0; e < E_; ++e) c += bqkv[512 + e] * bmlp[e];
      *cconst = c;
    }
  }
}

// ---------------------------------------------------------------- K1: precompute GEMM (3 tensors)
__global__ __launch_bounds__(256, 2)
void k_gemm(const float* __restrict__ emb, const float* __restrict__ Wqkv,
            const float* __restrict__ bqkv,
            const float* __restrict__ Wc, const float* __restrict__ bc,
            float* __restrict__ kk_, float* __restrict__ vv_,
            float* __restrict__ lk2, int ncc, int tmask) {
  __shared__ float As[256 * 64];  // [kk][m], exactly 64 KiB
  int t = threadIdx.x;
  int r0 = blockIdx.x * 64;
  {
    int m = t >> 2;
    int c0 = t & 3;
    const float4* e4 = (const float4*)emb;
#pragma unroll
    for (int p = 0; p < 16; ++p) {
      int c4 = c0 + p * 4;
      float4 a = e4[(size_t)(r0 + m) * 64 + c4];
      As[(c4 * 4 + 0) * 64 + m] = a.x;
      As[(c4 * 4 + 1) * 64 + m] = a.y;
      As[(c4 * 4 + 2) * 64 + m] = a.z;
      As[(c4 * 4 + 3) * 64 + m] = a.w;
    }
  }
  __syncthreads();
  int tx = t & 15, ty = t >> 4;
  const float4* As4 = (const float4*)As;
  for (int cc = 0; cc < ncc; ++cc) {
    const float* Bp; int ldb4; const float* bias; float* outp;
    int colbase = (cc & 1) * 128;
    switch (cc >> 1) {
      case 0:  Bp = Wqkv + colbase;          ldb4 = 192; bias = bqkv + colbase;       outp = kk_; break;
      case 1:  Bp = Wqkv + 256 + colbase;    ldb4 = 192; bias = bqkv + 256 + colbase; outp = vv_; break;
      default: Bp = Wc + colbase;            ldb4 = 64;  bias = bc + colbase;         outp = lk2; break;
    }
    const float4* B4 = (const float4*)Bp;
    float acc[4][8];
#pragma unroll
    for (int i = 0; i < 4; ++i)
#pragma unroll
      for (int j = 0; j < 8; ++j) acc[i][j] = 0.f;

#pragma unroll 4
    for (int kk = 0; kk < 256; ++kk) {
      float4 b0 = B4[kk * ldb4 + tx * 2];
      float4 b1 = B4[kk * ldb4 + tx * 2 + 1];
      float4 av = As4[kk * 16 + ty];
      float a_[4] = {av.x, av.y, av.z, av.w};
#pragma unroll
      for (int i = 0; i < 4; ++i) {
        acc[i][0] += a_[i] * b0.x; acc[i][1] += a_[i] * b0.y;
        acc[i][2] += a_[i] * b0.z; acc[i][3] += a_[i] * b0.w;
        acc[i][4] += a_[i] * b1.x; acc[i][5] += a_[i] * b1.y;
        acc[i][6] += a_[i] * b1.z; acc[i][7] += a_[i] * b1.w;
      }
    }
    float bj[8];
#pragma unroll
    for (int j = 0; j < 8; ++j) bj[j] = bias ? bias[tx * 8 + j] : 0.f;
    int tr = (tmask >> (cc >> 1)) & 1;
    if (!tr) {
#pragma unroll
      for (int i = 0; i < 4; ++i) {
        int row = r0 + ty * 4 + i;
        float4 o0 = make_float4(acc[i][0] + bj[0], acc[i][1] + bj[1], acc[i][2] + bj[2], acc[i][3] + bj[3]);
        float4 o1 = make_float4(acc[i][4] + bj[4], acc[i][5] + bj[5], acc[i][6] + bj[6], acc[i][7] + bj[7]);
        float4* o4 = (float4*)(outp + (size_t)row * 256 + colbase + tx * 8);
        o4[0] = o0; o4[1] = o1;
      }
    } else {
#pragma unroll
      for (int i = 0; i < 4; ++i) {
        int row = r0 + ty * 4 + i;
        int bb = row >> 7, nn = row & 127;
        float* op = outp + (size_t)bb * 32768 + nn;
#pragma unroll
        for (int j = 0; j < 8; ++j)
          op[(size_t)(colbase + tx * 8 + j) * 128] = acc[i][j] + bj[j];
      }
    }
  }
}

// ---------------------------------------------------------------- K2: qbase per b
__global__ void k_qbase(const float* __restrict__ emb, const float* __restrict__ Wfix,
                        const float* __restrict__ bfix, const float* __restrict__ Wstep,
                        const float* __restrict__ bstep, float* __restrict__ qbase) {
  int b = blockIdx.x, t = threadIdx.x;
  __shared__ float ge[E_], fi[E_];
  const float* eb = emb + (size_t)b * N_ * E_;
  float s = 0.f;
#pragma unroll 8
  for (int n = 0; n < N_; ++n) s += eb[n * E_ + t];
  ge[t] = s * (1.0f / 128.0f);
  fi[t] = eb[t];
  __syncthreads();
  float acc = bfix[t] + bstep[t];
#pragma unroll 4
  for (int g = 0; g < E_; ++g)
    acc += ge[g] * Wfix[g * E_ + t] + fi[g] * Wstep[g * E_ + t];
  qbase[b * E_ + t] = acc;
}

// ---------------------------------------------------------------- K3: c[b,n]
__global__ void k_c(const float* __restrict__ emb, const float* __restrict__ wc2,
                    const float* __restrict__ cconst, float* __restrict__ cvec) {
  __shared__ float w[E_];
  int t = threadIdx.x;
  w[t] = wc2[t];
  __syncthreads();
  int row = blockIdx.x * 256 + t;
  const float4* e4 = (const float4*)(emb + (size_t)row * E_);
  const float4* w4 = (const float4*)w;
  float acc = 0.f;
#pragma unroll 8
  for (int j = 0; j < E_ / 4; ++j) {
    float4 a = e4[j], bv = w4[j];
    acc += a.x * bv.x + a.y * bv.y + a.z * bv.z + a.w * bv.w;
  }
  cvec[row] = acc + *cconst;
}

// ---------------------------------------------------------------- K4: wave-per-head rollout
// One block (512 thr, 8 waves) per batch element. Wave h == head h.
// __launch_bounds__(512, 1): LDS caps occupancy at 1 block/CU regardless, so allow
// the full 512-VGPR budget -> k/v/lk2 arrays stay truly register-resident.
__global__ __launch_bounds__(512, 1)
void k_roll(const float* __restrict__ emb, const float* __restrict__ Wstep,
            const float* __restrict__ kT, const float* __restrict__ vv_,
            const float* __restrict__ lkT,
            const float* __restrict__ qbase, const float* __restrict__ cvec,
            float* __restrict__ out) {
  int lt = threadIdx.x;
  int b = blockIdx.x;
  int h = lt >> 6;      // wave = head
  int j = lt & 63;      // lane

  __shared__ float sq_lds[128 * 260];   // 130 KiB (stride 260: init-store bank spread)
  __shared__ float work[6144];          // 24 KiB overlay: init At/Bs | at_s/ctx_s/zp
  float* at_s  = work;                  // [8][128] wave-private slices
  float* ctx_s = work + 1024;           // [8][32]  wave-private slices
  float* zp    = work + 1280;           // [2][8][128] double-buffered

  // ---- init: sq_lds[n][e] = qbase[b][e] + sum_g emb[b][n][g] * Wstep[256+g][e]
  {
    float* At = work;           // [16][128]
    float* Bs = work + 2048;    // [16][256]
    const float4* eb4 = (const float4*)(emb + (size_t)b * 32768);
    const float* W2 = Wstep + 65536;
    int n0 = (lt & 31) * 4;
    int e0 = (lt >> 5) * 16;
    float acc[4][16];
#pragma unroll
    for (int i = 0; i < 4; ++i)
#pragma unroll
      for (int jj = 0; jj < 16; ++jj) acc[i][jj] = 0.f;

    for (int gc = 0; gc < 16; ++gc) {
      {
        int n = lt & 127, q4g = lt >> 7;
        float4 a = eb4[n * 64 + gc * 4 + q4g];
        At[(q4g * 4 + 0) * 128 + n] = a.x;
        At[(q4g * 4 + 1) * 128 + n] = a.y;
        At[(q4g * 4 + 2) * 128 + n] = a.z;
        At[(q4g * 4 + 3) * 128 + n] = a.w;
      }
      {
        const float4* w4 = (const float4*)(W2 + gc * 16 * 256);
        ((float4*)Bs)[lt] = w4[lt];
        ((float4*)Bs)[lt + 512] = w4[lt + 512];
      }
      __syncthreads();
#pragma unroll
      for (int gi = 0; gi < 16; ++gi) {
        float4 a4 = *(const float4*)(At + gi * 128 + n0);
        const float4* bp = (const float4*)(Bs + gi * 256 + e0);
        float4 b0 = bp[0], b1 = bp[1], b2 = bp[2], b3 = bp[3];
        float av[4] = {a4.x, a4.y, a4.z, a4.w};
        float bv[16] = {b0.x, b0.y, b0.z, b0.w, b1.x, b1.y, b1.z, b1.w,
                        b2.x, b2.y, b2.z, b2.w, b3.x, b3.y, b3.z, b3.w};
#pragma unroll
        for (int i = 0; i < 4; ++i)
#pragma unroll
          for (int jj = 0; jj < 16; ++jj) acc[i][jj] += av[i] * bv[jj];
      }
      __syncthreads();
    }
    const float* qb = qbase + (size_t)b * 256;
    float qbr[16];
#pragma unroll
    for (int jj = 0; jj < 16; ++jj) qbr[jj] = qb[e0 + jj];
#pragma unroll
    for (int i = 0; i < 4; ++i)
#pragma unroll
      for (int jj = 0; jj < 16; ++jj)
        sq_lds[(n0 + i) * 260 + e0 + jj] = acc[i][jj] + qbr[jj];  // scalar: 2-way banks
  }
  __syncthreads();
  __builtin_amdgcn_sched_barrier(0);   // keep init acc[] live range from overlapping fills

  // ---- register fills (coalesced within 32/64-lane groups) ----
  const float* kTb = kT + (size_t)b * 32768;
  const float* vb  = vv_ + (size_t)b * 32768;
  const float* lTb = lkT + (size_t)b * 32768;

  float k0r[32], k1r[32];     // k[h][d][j], k[h][d][j+64]
#pragma unroll
  for (int d = 0; d < 32; ++d) {
    k0r[d] = kTb[(h * 32 + d) * 128 + j];
    k1r[d] = kTb[(h * 32 + d) * 128 + j + 64];
  }
  int e_own = h * 32 + (j & 31), nh = j >> 5;
  float vr[64];               // v[nh*64+m][e_own]
#pragma unroll
  for (int m = 0; m < 64; ++m) vr[m] = vb[(nh * 64 + m) * 256 + e_own];
  float l0r[32], l1r[32];     // lk2[j][h-slice], lk2[j+64][h-slice]
#pragma unroll
  for (int e = 0; e < 32; ++e) {
    l0r[e] = lTb[(h * 32 + e) * 128 + j];
    l1r[e] = lTb[(h * 32 + e) * 128 + j + 64];
  }
  float cv_lo = cvec[b * 128 + j];
  float cv_hi = cvec[b * 128 + j + 64];
  int vis_lo = (j == 0) ? 1 : 0, vis_hi = 0;
  int cur = 0;
  float lp = 0.f;

#pragma unroll 1
  for (int it = 0; it < N_ - 1; ++it) {
    // --- scores (wave-local; q row broadcast-read from sq_lds) ---
    const float4* q4 = (const float4*)(sq_lds + cur * 260 + h * 32);
    float sa0 = 0.f, sb0 = 0.f, sa1 = 0.f, sb1 = 0.f;
#pragma unroll
    for (int dd = 0; dd < 8; ++dd) {
      float4 qv = q4[dd];
      if (dd & 1) {
        sb0 += qv.x * k0r[dd * 4] + qv.y * k0r[dd * 4 + 1] + qv.z * k0r[dd * 4 + 2] + qv.w * k0r[dd * 4 + 3];
        sb1 += qv.x * k1r[dd * 4] + qv.y * k1r[dd * 4 + 1] + qv.z * k1r[dd * 4 + 2] + qv.w * k1r[dd * 4 + 3];
      } else {
        sa0 += qv.x * k0r[dd * 4] + qv.y * k0r[dd * 4 + 1] + qv.z * k0r[dd * 4 + 2] + qv.w * k0r[dd * 4 + 3];
        sa1 += qv.x * k1r[dd * 4] + qv.y * k1r[dd * 4 + 1] + qv.z * k1r[dd * 4 + 2] + qv.w * k1r[dd * 4 + 3];
      }
    }
    float slo = vis_lo ? NEG : (sa0 + sb0) * SCALE;
    float shi = vis_hi ? NEG : (sa1 + sb1) * SCALE;
    // --- softmax (in-wave; division deferred) ---
    float m = wred_max(fmaxf(slo, shi));
    float elo = expf(slo - m), ehi = expf(shi - m);
    at_s[h * 128 + j] = elo;
    at_s[h * 128 + 64 + j] = ehi;
    float inv = 1.0f / wred_sum(elo + ehi);
    // --- ctx for e_own over n-half (wave-local LDS read, no barrier) ---
    const float4* a4 = (const float4*)(at_s + h * 128 + nh * 64);
    float c0 = 0.f, c1 = 0.f;
#pragma unroll
    for (int mm = 0; mm < 16; ++mm) {
      float4 av = a4[mm];
      if (mm & 1)
        c1 += av.x * vr[mm * 4] + av.y * vr[mm * 4 + 1] + av.z * vr[mm * 4 + 2] + av.w * vr[mm * 4 + 3];
      else
        c0 += av.x * vr[mm * 4] + av.y * vr[mm * 4 + 1] + av.z * vr[mm * 4 + 2] + av.w * vr[mm * 4 + 3];
    }
    float c = c0 + c1;
    c += __shfl_xor(c, 32);     // combine n-halves (lanes j, j^32 share e_own)
    c *= inv;
    if (j < 32) ctx_s[h * 32 + j] = c;
    // --- z partial for head-slice (wave-local broadcast read) ---
    const float4* cx4 = (const float4*)(ctx_s + h * 32);
    float z0a = 0.f, z0b = 0.f, z1a = 0.f, z1b = 0.f;
#pragma unroll
    for (int ee = 0; ee < 8; ++ee) {
      float4 cv = cx4[ee];
      if (ee & 1) {
        z0b += cv.x * l0r[ee * 4] + cv.y * l0r[ee * 4 + 1] + cv.z * l0r[ee * 4 + 2] + cv.w * l0r[ee * 4 + 3];
        z1b += cv.x * l1r[ee * 4] + cv.y * l1r[ee * 4 + 1] + cv.z * l1r[ee * 4 + 2] + cv.w * l1r[ee * 4 + 3];
      } else {
        z0a += cv.x * l0r[ee * 4] + cv.y * l0r[ee * 4 + 1] + cv.z * l0r[ee * 4 + 2] + cv.w * l0r[ee * 4 + 3];
        z1a += cv.x * l1r[ee * 4] + cv.y * l1r[ee * 4 + 1] + cv.z * l1r[ee * 4 + 2] + cv.w * l1r[ee * 4 + 3];
      }
    }
    float* zpw = zp + (it & 1) * 1024;
    zpw[h * 128 + j] = z0a + z0b;
    zpw[h * 128 + 64 + j] = z1a + z1b;
    __syncthreads();   // the ONLY barrier per step

    // --- phase C: every wave redundantly assembles z, argmax (ballot tiebreak), lse ---
    float zlo = cv_lo, zhi = cv_hi;
#pragma unroll
    for (int hh = 0; hh < 8; ++hh) {
      zlo += zpw[hh * 128 + j];
      zhi += zpw[hh * 128 + 64 + j];
    }
    float zmlo = vis_lo ? -1e30f : zlo;
    float zmhi = vis_hi ? -1e30f : zhi;
    float vmax = wred_max(fmaxf(zmlo, zmhi));
    unsigned long long blo = __ballot(zmlo == vmax);
    int action;
    if (blo) action = __ffsll((unsigned long long)blo) - 1;
    else     action = 63 + __ffsll((unsigned long long)__ballot(zmhi == vmax));
    float lmax = CLIPV * tanhf(vmax * SCALE);
    float tlo = vis_lo ? 0.f : expf(CLIPV * tanhf(zlo * SCALE) - 10.0f);
    float thi = vis_hi ? 0.f : expf(CLIPV * tanhf(zhi * SCALE) - 10.0f);
    float S = wred_sum(tlo + thi);
    lp += lmax - 10.0f - logf(S);
    cur = action;
    vis_lo |= (action == j);
    vis_hi |= (action == j + 64);
  }
  if (lt == 0) out[b] = lp;
}

// ---------------------------------------------------------------- launch
extern "C" void kernel_launch(void* const* d_in, const int* in_sizes, int n_in,
                              void* d_out, int out_size, void* d_ws, size_t ws_size,
                              hipStream_t stream) {
  (void)in_sizes; (void)n_in; (void)out_size; (void)ws_size;
  const float* emb   = (const float*)d_in[0];
  const float* Wqkv  = (const float*)d_in[1];
  const float* bqkv  = (const float*)d_in[2];
  const float* Wfix  = (const float*)d_in[3];
  const float* bfix  = (const float*)d_in[4];
  const float* Wstep = (const float*)d_in[5];
  const float* bstep = (const float*)d_in[6];
  const float* Wmlp  = (const float*)d_in[7];
  const float* bmlp  = (const float*)d_in[8];
  float* out = (float*)d_out;
  float* ws = (float*)d_ws;

  const size_t NBE = (size_t)B_ * N_ * E_;  // 16,777,216 floats
  float* kk_    = ws;                  // kT
  float* vv_    = ws + NBE;            // v
  float* lk2    = ws + 2 * NBE;        // lkT
  float* qbase  = ws + 3 * NBE;        // 131072
  float* cvec   = qbase + 131072;      // 65536
  float* Wc     = cvec + 65536;        // 65536
  float* bc     = Wc + 65536;          // 256
  float* wc2    = bc + 256;            // 256
  float* cconst = wc2 + 256;           // (64 pad)

  hipLaunchKernelGGL(k0_prep, dim3(257), dim3(256), 0, stream,
                     Wqkv, bqkv, Wmlp, bmlp, Wc, bc, wc2, cconst);
  hipLaunchKernelGGL(k_qbase, dim3(512), dim3(256), 0, stream,
                     emb, Wfix, bfix, Wstep, bstep, qbase);
  hipLaunchKernelGGL(k_c, dim3(256), dim3(256), 0, stream,
                     emb, wc2, cconst, cvec);
  hipLaunchKernelGGL(k_gemm, dim3(1024), dim3(256), 0, stream,
                     emb, Wqkv, bqkv, Wc, bc, kk_, vv_, lk2, 6, 0b101);
  hipLaunchKernelGGL(k_roll, dim3(512), dim3(512), 0, stream,
                     emb, Wstep, kk_, vv_, lk2, qbase, cvec, out);
}